// Round 10
// baseline (914.851 us; speedup 1.0000x reference)
//
#include <hip/hip_runtime.h>
#include <hip/hip_bf16.h>
#include <stdint.h>

// Problem constants
#define BB 4
#define TT 4096
#define DD 2048
#define MM (BB*TT)   // 16384 rows
#define WC 64        // wkv chunks per sequence
#define WL 64        // wkv chunk length (WC*WL == TT)

typedef __bf16 bf16x8 __attribute__((ext_vector_type(8)));
typedef __bf16 bf16x2 __attribute__((ext_vector_type(2)));
typedef float  f32x4  __attribute__((ext_vector_type(4)));

__device__ __forceinline__ void g2l16(const void* g, void* l) {
  __builtin_amdgcn_global_load_lds(
      (const __attribute__((address_space(1))) void*)g,
      (__attribute__((address_space(3))) void*)l,
      16, 0, 0);
}

// ---------------------------------------------------------------------------
// Kernel 0: dtype detect + convert small vectors to fp32.
// ---------------------------------------------------------------------------
__global__ void detect_small_kernel(const void* __restrict__ tdec_raw,
                                    const void* __restrict__ tfirst_raw,
                                    const void* __restrict__ lng_raw,
                                    const void* __restrict__ lnb_raw,
                                    const void* __restrict__ tmk_raw,
                                    const void* __restrict__ tmv_raw,
                                    const void* __restrict__ tmr_raw,
                                    int* __restrict__ flag,
                                    float* __restrict__ tdecF,
                                    float* __restrict__ tfirstF,
                                    float* __restrict__ lngF,
                                    float* __restrict__ lnbF,
                                    float* __restrict__ tmkF,
                                    float* __restrict__ tmvF,
                                    float* __restrict__ tmrF)
{
  const uint32_t w0 = *(const uint32_t*)tdec_raw;
  const int isf32 = ((w0 & 0xFFFFu) == 0u) ? 1 : 0;
  if (threadIdx.x == 0) *flag = isf32;
  for (int d = threadIdx.x; d < DD; d += blockDim.x) {
    if (isf32) {
      tdecF[d]   = ((const float*)tdec_raw)[d];
      tfirstF[d] = ((const float*)tfirst_raw)[d];
      lngF[d]    = ((const float*)lng_raw)[d];
      lnbF[d]    = ((const float*)lnb_raw)[d];
      tmkF[d]    = ((const float*)tmk_raw)[d];
      tmvF[d]    = ((const float*)tmv_raw)[d];
      tmrF[d]    = ((const float*)tmr_raw)[d];
    } else {
      tdecF[d]   = (float)((const __bf16*)tdec_raw)[d];
      tfirstF[d] = (float)((const __bf16*)tfirst_raw)[d];
      lngF[d]    = (float)((const __bf16*)lng_raw)[d];
      lnbF[d]    = (float)((const __bf16*)lnb_raw)[d];
      tmkF[d]    = (float)((const __bf16*)tmk_raw)[d];
      tmvF[d]    = (float)((const __bf16*)tmv_raw)[d];
      tmrF[d]    = (float)((const __bf16*)tmr_raw)[d];
    }
  }
}

// ---------------------------------------------------------------------------
// Kernel 0b: convert one DxD weight matrix to canonical bf16
// ---------------------------------------------------------------------------
__global__ void convert_w_kernel(const void* __restrict__ src,
                                 __bf16* __restrict__ dst,
                                 const int* __restrict__ flagp)
{
  const int isf32 = *flagp;
  const int64_t NV = (int64_t)DD * DD / 8;
  for (int64_t v = blockIdx.x * (int64_t)blockDim.x + threadIdx.x;
       v < NV; v += (int64_t)gridDim.x * blockDim.x) {
    const int64_t i = v * 8;
    bf16x8 o;
    if (isf32) {
      const float* sf = (const float*)src;
      f32x4 a = *(const f32x4*)(sf + i);
      f32x4 b = *(const f32x4*)(sf + i + 4);
      #pragma unroll
      for (int e = 0; e < 4; e++) { o[e] = (__bf16)a[e]; o[e+4] = (__bf16)b[e]; }
    } else {
      o = *(const bf16x8*)((const __bf16*)src + i);
    }
    *(bf16x8*)(dst + i) = o;
  }
}

// ---------------------------------------------------------------------------
// Kernel 1: token-shift mix -> xk, xv, xr (bf16)
// ---------------------------------------------------------------------------
__global__ void mix_kernel(const void* __restrict__ xraw,
                           const float* __restrict__ tmkF,
                           const float* __restrict__ tmvF,
                           const float* __restrict__ tmrF,
                           const int* __restrict__ flagp,
                           __bf16* __restrict__ xk,
                           __bf16* __restrict__ xv,
                           __bf16* __restrict__ xr)
{
  const int isf32 = *flagp;
  const int64_t NV = (int64_t)MM * DD / 8;
  for (int64_t v = blockIdx.x * (int64_t)blockDim.x + threadIdx.x;
       v < NV; v += (int64_t)gridDim.x * blockDim.x) {
    const int64_t i = v * 8;
    const int d = (int)(i & (DD - 1));
    const int64_t td = i & ((int64_t)TT * DD - 1);
    const bool has_prev = (td >= DD);
    float xc[8], xp[8];
    if (isf32) {
      const float* xf = (const float*)xraw;
      f32x4 a = *(const f32x4*)(xf + i);
      f32x4 b = *(const f32x4*)(xf + i + 4);
      #pragma unroll
      for (int e = 0; e < 4; e++) { xc[e] = a[e]; xc[e+4] = b[e]; }
      if (has_prev) {
        f32x4 c = *(const f32x4*)(xf + i - DD);
        f32x4 dd4 = *(const f32x4*)(xf + i - DD + 4);
        #pragma unroll
        for (int e = 0; e < 4; e++) { xp[e] = c[e]; xp[e+4] = dd4[e]; }
      } else {
        #pragma unroll
        for (int e = 0; e < 8; e++) xp[e] = 0.f;
      }
    } else {
      const __bf16* xb = (const __bf16*)xraw;
      bf16x8 a = *(const bf16x8*)(xb + i);
      #pragma unroll
      for (int e = 0; e < 8; e++) xc[e] = (float)a[e];
      if (has_prev) {
        bf16x8 c = *(const bf16x8*)(xb + i - DD);
        #pragma unroll
        for (int e = 0; e < 8; e++) xp[e] = (float)c[e];
      } else {
        #pragma unroll
        for (int e = 0; e < 8; e++) xp[e] = 0.f;
      }
    }
    bf16x8 ok, ov, orr;
    #pragma unroll
    for (int e = 0; e < 8; e++) {
      const float diff = xc[e] - xp[e];
      ok[e]  = (__bf16)(xp[e] + tmkF[d + e] * diff);
      ov[e]  = (__bf16)(xp[e] + tmvF[d + e] * diff);
      orr[e] = (__bf16)(xp[e] + tmrF[d + e] * diff);
    }
    *(bf16x8*)(xk + i) = ok;
    *(bf16x8*)(xv + i) = ov;
    *(bf16x8*)(xr + i) = orr;
  }
}

// ---------------------------------------------------------------------------
// Kernel 2: GEMM  C[m,n] = sum_k A[m,k] * Bm[n,k]   (B^T layout, bf16 MFMA)
//
// Round-10: break the register-file occupancy cap. Diagnosis: r3's kernel is
// 128 VGPR + 128 AGPR acc = 256 regs/wave (unified file) -> HW caps at
// 2 waves/SIMD (measured occ 21.7%), all barrier-locked in ONE block ->
// pipes serialize; pipe-time SUM (LDS-rd 61 + MFMA 60 + L2 31 + LDS-wr 14us)
// = 170us = the measured wall for every schedule tried.
//
// Fix: per-wave acc 64 regs (64x64 output): 128x256 tile, 8 waves (2Mx4N),
// BK=32, double-buffered 48 KiB LDS, launch_bounds(512,4) -> ~116 regs/wave
// -> 2 BLOCKS/CU, 4 waves/SIMD from INDEPENDENT blocks -> cross-block pipe
// overlap (m114) at a good traffic ratio + r8's A-reuse XCD map.
//
// LDS: buf p at elem p*12288: A[128][32] (4096 elems) + B[256][32] (8192).
// Swizzle (r6-verified 0-conflict for 64B rows): chunk c of row r at
// c^((r>>1)&3); inverse-swizzled global source; ds_read same XOR.
//
// Per tile t (CB=buf[t&1], OB=other), r3-style derived waits:
//   RD af(4),bfr(4); STAGE A(t+1)->OB (1 g2l); Q1 (af x bfr[0..1], 8 MFMA);
//   lgkmcnt(0); barrier            <- WAR cert: CB's B reads done
//   STAGE B(t+2)->CB (2 g2l); Q2 (af x bfr[2..3], 8 MFMA);
//   vmcnt(2); barrier              <- FIFO drains t+1.B(2)+t+1.A(1),
//                                     leaves t+2.B(2) in flight
// Invariant: entering tile t, buf[t&1] resident, exactly t+1.B outstanding.
// Never vmcnt(0) in loop. Kd==2048 -> 64 tiles at every call site.
// EPI: 0=f32, 1=final(flag?f32:bf16), 2=sigmoid->bf16, 3=bf16.
// ---------------------------------------------------------------------------
#define BARX()   __builtin_amdgcn_s_barrier()
#define SCHEDB() __builtin_amdgcn_sched_barrier(0)
#define WAITL(n) asm volatile("s_waitcnt lgkmcnt(" #n ")" ::: "memory")
#define WAITV(n) asm volatile("s_waitcnt vmcnt(" #n ")" ::: "memory")

// stage K-tile kt: A = 128 rows (1 g2l/thread), B = 256 rows (2 g2l/thread)
#define STG_A(PB, kt) \
    g2l16(Asrc + (size_t)(kt)*32, smem + (PB) + tid*8)
#define STG_B(PB, kt) do { \
    g2l16(Bsrc + (size_t)(kt)*32,                 smem + (PB) + 4096 + tid*8); \
    g2l16(Bsrc + (size_t)128*Kd + (size_t)(kt)*32, smem + (PB) + 8192 + tid*8); \
  } while (0)

#define RD_A(pb) do { _Pragma("unroll") for (int i_ = 0; i_ < 4; i_++) \
    af[i_] = *(const bf16x8*)(smem + (pb) + aoff + i_*512); } while (0)
#define RD_B(pb) do { _Pragma("unroll") for (int j_ = 0; j_ < 4; j_++) \
    bfr[j_] = *(const bf16x8*)(smem + (pb) + boff + j_*512); } while (0)

#define MFMA_J(J) do { _Pragma("unroll") for (int i_ = 0; i_ < 4; i_++) \
    acc[i_][J] = __builtin_amdgcn_mfma_f32_16x16x32_bf16(af[i_], bfr[J], acc[i_][J], 0, 0, 0); } while (0)

#define TILE32(CB, OB, tA, tB) do { \
    RD_A(CB); RD_B(CB); \
    STG_A(OB, tA); \
    __builtin_amdgcn_s_setprio(1); \
    MFMA_J(0); MFMA_J(1); \
    __builtin_amdgcn_s_setprio(0); \
    WAITL(0); \
    BARX(); \
    SCHEDB(); \
    STG_B(CB, tB); \
    __builtin_amdgcn_s_setprio(1); \
    MFMA_J(2); MFMA_J(3); \
    __builtin_amdgcn_s_setprio(0); \
    WAITV(2); \
    BARX(); \
    SCHEDB(); \
  } while (0)

template <int EPI>
__global__ void __launch_bounds__(512, 4)
gemm_bt(const __bf16* __restrict__ A,
        const __bf16* __restrict__ Bm,
        void* __restrict__ Cout,
        const int* __restrict__ flagp,
        int Md, int Nd, int Kd)
{
  __shared__ __bf16 smem[24576];   // 48 KiB -> 2 blocks/CU
  const int isf32 = (EPI == 1) ? *flagp : 0;
  const int tid  = threadIdx.x;    // 0..511
  const int lane = tid & 63;
  const int wv   = tid >> 6;       // 0..7
  const int wm   = wv >> 2;        // wave row 0..1 (64 rows each)
  const int wn   = wv & 3;         // wave col 0..3 (64 cols each)
  const int l16  = lane & 15;
  const int qd   = lane >> 4;

  // A-reuse XCD map (r8, FETCH 292->119MB measured): the 8 colblk-sharers of
  // one A panel are stride-8 in bid -> same XCD; resident A window/XCD =
  // ~8 x 0.5MB = 4MB = L2.
  const int bid    = blockIdx.x;          // 0..1023
  const int xcd    = bid & 7;
  const int colblk = (bid >> 3) & 7;
  const int rowsub = bid >> 6;            // 0..15
  const int row0   = (xcd * 16 + rowsub) * 128;
  const int col0   = colblk * 256;

  // staging: thread -> row tid>>2 (0..127), phys chunk tid&3; global chunk
  // inverse-swizzled with row bits [2:1] (r6 pattern, 0 conflicts measured).
  // B's second half rows +128: (+128>>1)&3 == +0 mod 4 -> same XOR.
  const int srow   = tid >> 2;
  const int schunk = (tid & 3) ^ ((srow >> 1) & 3);
  const __bf16* Asrc = A  + (size_t)(row0 + srow) * Kd + schunk * 8;
  const __bf16* Bsrc = Bm + (size_t)(col0 + srow) * Kd + schunk * 8;

  // ds_read: fragment row = w*64 + f*16 + l16 -> (row>>1)&3 == (l16>>1)&3
  const int c0   = (qd ^ ((l16 >> 1) & 3)) * 8;
  const int aoff = (wm * 64 + l16) * 32 + c0;
  const int boff = 4096 + (wn * 64 + l16) * 32 + c0;

  f32x4 acc[4][4];
  #pragma unroll
  for (int i = 0; i < 4; i++)
    #pragma unroll
    for (int j = 0; j < 4; j++)
      acc[i][j] = (f32x4){0.f, 0.f, 0.f, 0.f};

  bf16x8 af[4], bfr[4];

  // Prologue: tile0 A+B -> buf0, tile1 B -> buf1. Outstanding 5; WAITV(2)
  // drains A0,B0 (FIFO), leaves tile1.B (2) = steady-state invariant.
  STG_A(0, 0);
  STG_B(0, 0);
  STG_B(12288, 1);
  WAITV(2);
  BARX();
  SCHEDB();

  // 64 K-tiles. Main loop t=0..61 (stages A(1..62), B(2..63)); tail 62,63.
  #pragma unroll 1
  for (int it = 0; it < 31; ++it) {
    const int t = it << 1;
    TILE32(0,     12288, t + 1, t + 2);
    TILE32(12288, 0,     t + 2, t + 3);
  }

  // tile 62 (buf0): stage only A(63)->buf1 (B(63) staged at t=61); drain.
  {
    RD_A(0); RD_B(0);
    STG_A(12288, 63);
    __builtin_amdgcn_s_setprio(1);
    MFMA_J(0); MFMA_J(1); MFMA_J(2); MFMA_J(3);
    __builtin_amdgcn_s_setprio(0);
    WAITV(0);
    BARX();
    SCHEDB();
  }
  // tile 63 (buf1): no staging, no barriers.
  {
    RD_A(12288); RD_B(12288);
    __builtin_amdgcn_s_setprio(1);
    MFMA_J(0); MFMA_J(1); MFMA_J(2); MFMA_J(3);
    __builtin_amdgcn_s_setprio(0);
  }

  // epilogue: C/D layout col=lane&15, row=quad*4+reg (verified m89/m91)
  #pragma unroll
  for (int i = 0; i < 4; i++) {
    const int rb = row0 + wm * 64 + i * 16 + qd * 4;
    #pragma unroll
    for (int j = 0; j < 4; j++) {
      const int c = col0 + wn * 64 + j * 16 + l16;
      #pragma unroll
      for (int reg = 0; reg < 4; reg++) {
        const size_t idx = (size_t)(rb + reg) * Nd + c;
        float v = acc[i][j][reg];
        if (EPI == 0) {
          ((float*)Cout)[idx] = v;
        } else if (EPI == 1) {
          if (isf32) ((float*)Cout)[idx] = v;
          else       ((__bf16*)Cout)[idx] = (__bf16)v;
        } else if (EPI == 3) {
          ((__bf16*)Cout)[idx] = (__bf16)v;
        } else {
          float s = 1.f / (1.f + __expf(-v));
          ((__bf16*)Cout)[idx] = (__bf16)s;
        }
      }
    }
  }
}

// ---------------------------------------------------------------------------
// WKV parallel log-sum-exp prefix sum: part + scan (2-wide, unchanged from
// r9 except prefix arrays relocated by the launcher).
// ---------------------------------------------------------------------------
__global__ void wkv_part_kernel(const float* __restrict__ Kb,
                                const __bf16* __restrict__ Vb,
                                float* __restrict__ pM,
                                float* __restrict__ pA,
                                float* __restrict__ pB)
{
  const int gid = blockIdx.x * blockDim.x + threadIdx.x;  // 0..B*WC*D/2-1
  const int d = (gid & (DD / 2 - 1)) * 2;
  const int rest = gid >> 10;
  const int c = rest & (WC - 1);
  const int b = rest >> 6;
  const float*  kp = Kb + ((size_t)b * TT + (size_t)c * WL) * DD + d;
  const __bf16* vp = Vb + ((size_t)b * TT + (size_t)c * WL) * DD + d;
  float M0 = -1e38f, A0 = 0.f, B0 = 0.f;
  float M1 = -1e38f, A1 = 0.f, B1 = 0.f;
  for (int t = 0; t < WL; t++) {
    const float2 k2 = *(const float2*)(kp + (size_t)t * DD);
    const bf16x2 v2 = *(const bf16x2*)(vp + (size_t)t * DD);
    {
      const float q = fmaxf(M0, k2.x);
      const float s = __expf(M0 - q);
      const float e = __expf(k2.x - q);
      A0 = A0 * s + e * (float)v2[0];
      B0 = B0 * s + e;
      M0 = q;
    }
    {
      const float q = fmaxf(M1, k2.y);
      const float s = __expf(M1 - q);
      const float e = __expf(k2.y - q);
      A1 = A1 * s + e * (float)v2[1];
      B1 = B1 * s + e;
      M1 = q;
    }
  }
  const size_t pi = ((size_t)b * WC + c) * DD + d;
  *(float2*)(pM + pi) = make_float2(M0, M1);
  *(float2*)(pA + pi) = make_float2(A0, A1);
  *(float2*)(pB + pi) = make_float2(B0, B1);
}

__global__ void wkv_scan_kernel(float* __restrict__ pM,
                                float* __restrict__ pA,
                                float* __restrict__ pB)
{
  const int gid = blockIdx.x * blockDim.x + threadIdx.x;  // 0..B*D/2-1
  const int d = (gid & (DD / 2 - 1)) * 2;
  const int b = gid >> 10;
  float M0 = -1e38f, A0 = 0.f, B0 = 0.f;
  float M1 = -1e38f, A1 = 0.f, B1 = 0.f;
  for (int c = 0; c < WC; c++) {
    const size_t pi = ((size_t)b * WC + c) * DD + d;
    const float2 m2 = *(const float2*)(pM + pi);
    const float2 a2 = *(const float2*)(pA + pi);
    const float2 b2 = *(const float2*)(pB + pi);
    *(float2*)(pM + pi) = make_float2(M0, M1);
    *(float2*)(pA + pi) = make_float2(A0, A1);
    *(float2*)(pB + pi) = make_float2(B0, B1);
    {
      const float q = fmaxf(M0, m2.x);
      const float s0 = __expf(M0 - q);
      const float s1 = __expf(m2.x - q);
      A0 = A0 * s0 + a2.x * s1;
      B0 = B0 * s0 + b2.x * s1;
      M0 = q;
    }
    {
      const float q = fmaxf(M1, m2.y);
      const float s0 = __expf(M1 - q);
      const float s1 = __expf(m2.y - q);
      A1 = A1 * s0 + a2.y * s1;
      B1 = B1 * s0 + b2.y * s1;
      M1 = q;
    }
  }
}

// ---------------------------------------------------------------------------
// Round-10 fused kernel: wkv_out + LayerNorm + r-multiply -> rwkv (bf16).
// One block per (b, chunk): 1024 threads x 2 d-values = full D row; loop the
// 64 t's of the chunk, computing wkv in f32, block-reducing LN stats, and
// writing r * LN(wkv) directly. Eliminates the ln kernel and the 64 MB Wkv
// round-trip. LN stats now computed on f32 wkv (closer to reference than
// r9's bf16-rounded stats).
// ---------------------------------------------------------------------------
__global__ void __launch_bounds__(1024)
wkv_out_ln_kernel(const float* __restrict__ Kb,
                  const __bf16* __restrict__ Vb,
                  const float* __restrict__ pM,
                  const float* __restrict__ pA,
                  const float* __restrict__ pB,
                  const float* __restrict__ tfirstF,
                  const float* __restrict__ g,
                  const float* __restrict__ beta,
                  const __bf16* __restrict__ rbuf,
                  __bf16* __restrict__ out)
{
  const int blk = blockIdx.x;       // 0..B*WC-1
  const int c = blk & (WC - 1);
  const int b = blk >> 6;
  const int tid = threadIdx.x;      // 0..1023
  const int d = tid * 2;
  const int lane = tid & 63;
  const int wave = tid >> 6;        // 0..15

  const size_t pi = ((size_t)b * WC + c) * DD + d;
  float2 M2 = *(const float2*)(pM + pi);
  float2 A2 = *(const float2*)(pA + pi);
  float2 B2 = *(const float2*)(pB + pi);
  float M0 = M2.x, A0 = A2.x, B0 = B2.x;
  float M1 = M2.y, A1 = A2.y, B1 = B2.y;
  const float u0 = tfirstF[d];
  const float u1 = tfirstF[d + 1];
  const float g0 = g[d],    g1 = g[d + 1];
  const float be0 = beta[d], be1 = beta[d + 1];

  const size_t base = ((size_t)b * TT + (size_t)c * WL) * DD + d;
  const float*  kp = Kb + base;
  const __bf16* vp = Vb + base;
  const __bf16* rp = rbuf + base;
  __bf16*       op = out + base;

  __shared__ float ls[16], lsq[16];

  for (int t = 0; t < WL; t++) {
    const float2 k2 = *(const float2*)(kp + (size_t)t * DD);
    const bf16x2 v2 = *(const bf16x2*)(vp + (size_t)t * DD);
    float o0, o1;
    {
      const float v = (float)v2[0];
      const float ku = k2.x + u0;
      const float qo = fmaxf(M0, ku);
      const float so = __expf(M0 - qo);
      const float eo = __expf(ku - qo);
      o0 = __fdividef(A0 * so + v * eo, B0 * so + eo);
      const float q = fmaxf(M0, k2.x);
      const float s = __expf(M0 - q);
      const float e = __expf(k2.x - q);
      A0 = A0 * s + e * v;
      B0 = B0 * s + e;
      M0 = q;
    }
    {
      const float v = (float)v2[1];
      const float ku = k2.y + u1;
      const float qo = fmaxf(M1, ku);
      const float so = __expf(M1 - qo);
      const float eo = __expf(ku - qo);
      o1 = __fdividef(A1 * so + v * eo, B1 * so + eo);
      const float q = fmaxf(M1, k2.y);
      const float s = __expf(M1 - q);
      const float e = __expf(k2.y - q);
      A1 = A1 * s + e * v;
      B1 = B1 * s + e;
      M1 = q;
    }

    // block LN reduction over 2048 values
    float s = o0 + o1;
    float sq = o0 * o0 + o1 * o1;
    #pragma unroll
    for (int off = 1; off < 64; off <<= 1) {
      s  += __shfl_xor(s, off);
      sq += __shfl_xor(sq, off);
    }
    if (lane == 0) { ls[wave] = s; lsq[wave] = sq; }
    __syncthreads();
    // combine the 16 wave partials: each lane grabs one, shfl-reduce 16
    float s2  = ls[lane & 15];
    float sq2 = lsq[lane & 15];
    #pragma unroll
    for (int off = 1; off < 16; off <<= 1) {
      s2  += __shfl_xor(s2, off);
      sq2 += __shfl_xor(sq2, off);
    }
    const float mu = s2 * (1.f / DD);
    const float var = sq2 * (1.f / DD) - mu * mu;
    const float rs = rsqrtf(var + 1e-5f);

    const bf16x2 r2 = *(const bf16x2*)(rp + (size_t)t * DD);
    bf16x2 o2;
    o2[0] = (__bf16)((float)r2[0] * ((o0 - mu) * rs * g0 + be0));
    o2[1] = (__bf16)((float)r2[1] * ((o1 - mu) * rs * g1 + be1));
    *(bf16x2*)(op + (size_t)t * DD) = o2;
    __syncthreads();   // protect ls/lsq before next iteration overwrites
  }
}

// ---------------------------------------------------------------------------
extern "C" void kernel_launch(void* const* d_in, const int* in_sizes, int n_in,
                              void* d_out, int out_size, void* d_ws, size_t ws_size,
                              hipStream_t stream) {
  const void* x      = d_in[0];
  const void* Wk     = d_in[1];
  const void* Wv     = d_in[2];
  const void* Wr     = d_in[3];
  const void* Wo     = d_in[4];
  const void* tmk    = d_in[5];
  const void* tmv    = d_in[6];
  const void* tmr    = d_in[7];
  const void* tdec   = d_in[8];
  const void* tfirst = d_in[9];
  const void* lng    = d_in[10];
  const void* lnb    = d_in[11];

  char* ws = (char*)d_ws;
  const size_t SZ_BF = (size_t)MM * DD * 2;   // 64 MiB
  const size_t SZ_F  = (size_t)MM * DD * 4;   // 128 MiB
  const size_t SZ_W  = (size_t)DD * DD * 2;   // 8 MiB
  __bf16* XK   = (__bf16*)(ws);
  __bf16* XV   = (__bf16*)(ws + SZ_BF);
  __bf16* XR   = (__bf16*)(ws + 2 * SZ_BF);
  float*  Kb   = (float*)(ws + 3 * SZ_BF);
  char*   VbSlot = ws + 3 * SZ_BF + SZ_F;            // 128 MiB slot
  __bf16* Vb   = (__bf16*)VbSlot;                    // bf16: first 64 MiB
  // prefix arrays in the FREE upper half of the Vb slot (2 MiB each) —
  // must NOT alias Rwkv (fused kernel reads prefixes while writing Rwkv).
  float* pM = (float*)(VbSlot + SZ_BF);
  float* pA = pM + (size_t)BB * WC * DD;
  float* pB = pA + (size_t)BB * WC * DD;
  __bf16* WkB  = (__bf16*)(ws + 3 * SZ_BF + 2 * SZ_F);
  __bf16* WvB  = (__bf16*)(ws + 3 * SZ_BF + 2 * SZ_F + SZ_W);
  __bf16* WrB  = (__bf16*)(ws + 3 * SZ_BF + 2 * SZ_F + 2 * SZ_W);
  __bf16* WoB  = (__bf16*)(ws + 3 * SZ_BF + 2 * SZ_F + 3 * SZ_W);
  char*   smal = ws + 3 * SZ_BF + 2 * SZ_F + 4 * SZ_W;
  int*    flag    = (int*)smal;
  float*  tdecF   = (float*)(smal + 64);
  float*  tfirstF = tdecF + DD;
  float*  lngF    = tdecF + 2 * DD;
  float*  lnbF    = tdecF + 3 * DD;
  float*  tmkF    = tdecF + 4 * DD;
  float*  tmvF    = tdecF + 5 * DD;
  float*  tmrF    = tdecF + 6 * DD;
  __bf16* Rwkv = (__bf16*)(ws + 2 * SZ_BF);    // over XR (dead after R-GEMM)
  __bf16* Rb   = (__bf16*)d_out;               // d_out as scratch until final GEMM

  detect_small_kernel<<<dim3(1), dim3(256), 0, stream>>>(
      tdec, tfirst, lng, lnb, tmk, tmv, tmr,
      flag, tdecF, tfirstF, lngF, lnbF, tmkF, tmvF, tmrF);

  convert_w_kernel<<<dim3(512), dim3(256), 0, stream>>>(Wk, WkB, flag);
  convert_w_kernel<<<dim3(512), dim3(256), 0, stream>>>(Wv, WvB, flag);
  convert_w_kernel<<<dim3(512), dim3(256), 0, stream>>>(Wr, WrB, flag);
  convert_w_kernel<<<dim3(512), dim3(256), 0, stream>>>(Wo, WoB, flag);

  mix_kernel<<<dim3(4096), dim3(256), 0, stream>>>(x, tmkF, tmvF, tmrF, flag, XK, XV, XR);

  // 128x256 tiles: (16384/128)*(2048/256) = 128*8 = 1024 blocks, 512 thr
  dim3 g(1024), blk(512);
  gemm_bt<0><<<g, blk, 0, stream>>>(XK, WkB, (void*)Kb, flag, MM, DD, DD);
  gemm_bt<3><<<g, blk, 0, stream>>>(XV, WvB, (void*)Vb, flag, MM, DD, DD);
  gemm_bt<2><<<g, blk, 0, stream>>>(XR, WrB, (void*)Rb, flag, MM, DD, DD);

  wkv_part_kernel<<<dim3(1024), dim3(256), 0, stream>>>(Kb, Vb, pM, pA, pB);
  wkv_scan_kernel<<<dim3(16), dim3(256), 0, stream>>>(pM, pA, pB);
  // fused out+LN+r: one block per (b, chunk)
  wkv_out_ln_kernel<<<dim3(BB * WC), dim3(1024), 0, stream>>>(
      Kb, Vb, pM, pA, pB, tfirstF, lngF, lnbF, Rb, Rwkv);

  gemm_bt<1><<<g, blk, 0, stream>>>(Rwkv, WoB, d_out, flag, MM, DD, DD);
}

// Round 11
// 880.940 us; speedup vs baseline: 1.0385x; 1.0385x over previous
//
#include <hip/hip_runtime.h>
#include <hip/hip_bf16.h>
#include <stdint.h>

// Problem constants
#define BB 4
#define TT 4096
#define DD 2048
#define MM (BB*TT)   // 16384 rows
#define WC 64        // wkv chunks per sequence
#define WL 64        // wkv chunk length (WC*WL == TT)

typedef __bf16 bf16x8 __attribute__((ext_vector_type(8)));
typedef __bf16 bf16x2 __attribute__((ext_vector_type(2)));
typedef float  f32x4  __attribute__((ext_vector_type(4)));

__device__ __forceinline__ void g2l16(const void* g, void* l) {
  __builtin_amdgcn_global_load_lds(
      (const __attribute__((address_space(1))) void*)g,
      (__attribute__((address_space(3))) void*)l,
      16, 0, 0);
}

// ---------------------------------------------------------------------------
// Kernel 0: dtype detect + convert small vectors to fp32.
// ---------------------------------------------------------------------------
__global__ void detect_small_kernel(const void* __restrict__ tdec_raw,
                                    const void* __restrict__ tfirst_raw,
                                    const void* __restrict__ lng_raw,
                                    const void* __restrict__ lnb_raw,
                                    const void* __restrict__ tmk_raw,
                                    const void* __restrict__ tmv_raw,
                                    const void* __restrict__ tmr_raw,
                                    int* __restrict__ flag,
                                    float* __restrict__ tdecF,
                                    float* __restrict__ tfirstF,
                                    float* __restrict__ lngF,
                                    float* __restrict__ lnbF,
                                    float* __restrict__ tmkF,
                                    float* __restrict__ tmvF,
                                    float* __restrict__ tmrF)
{
  const uint32_t w0 = *(const uint32_t*)tdec_raw;
  const int isf32 = ((w0 & 0xFFFFu) == 0u) ? 1 : 0;
  if (threadIdx.x == 0) *flag = isf32;
  for (int d = threadIdx.x; d < DD; d += blockDim.x) {
    if (isf32) {
      tdecF[d]   = ((const float*)tdec_raw)[d];
      tfirstF[d] = ((const float*)tfirst_raw)[d];
      lngF[d]    = ((const float*)lng_raw)[d];
      lnbF[d]    = ((const float*)lnb_raw)[d];
      tmkF[d]    = ((const float*)tmk_raw)[d];
      tmvF[d]    = ((const float*)tmv_raw)[d];
      tmrF[d]    = ((const float*)tmr_raw)[d];
    } else {
      tdecF[d]   = (float)((const __bf16*)tdec_raw)[d];
      tfirstF[d] = (float)((const __bf16*)tfirst_raw)[d];
      lngF[d]    = (float)((const __bf16*)lng_raw)[d];
      lnbF[d]    = (float)((const __bf16*)lnb_raw)[d];
      tmkF[d]    = (float)((const __bf16*)tmk_raw)[d];
      tmvF[d]    = (float)((const __bf16*)tmv_raw)[d];
      tmrF[d]    = (float)((const __bf16*)tmr_raw)[d];
    }
  }
}

// ---------------------------------------------------------------------------
// Kernel 0b: convert one DxD weight matrix to canonical bf16
// ---------------------------------------------------------------------------
__global__ void convert_w_kernel(const void* __restrict__ src,
                                 __bf16* __restrict__ dst,
                                 const int* __restrict__ flagp)
{
  const int isf32 = *flagp;
  const int64_t NV = (int64_t)DD * DD / 8;
  for (int64_t v = blockIdx.x * (int64_t)blockDim.x + threadIdx.x;
       v < NV; v += (int64_t)gridDim.x * blockDim.x) {
    const int64_t i = v * 8;
    bf16x8 o;
    if (isf32) {
      const float* sf = (const float*)src;
      f32x4 a = *(const f32x4*)(sf + i);
      f32x4 b = *(const f32x4*)(sf + i + 4);
      #pragma unroll
      for (int e = 0; e < 4; e++) { o[e] = (__bf16)a[e]; o[e+4] = (__bf16)b[e]; }
    } else {
      o = *(const bf16x8*)((const __bf16*)src + i);
    }
    *(bf16x8*)(dst + i) = o;
  }
}

// ---------------------------------------------------------------------------
// Kernel 1: token-shift mix -> xk, xv, xr (bf16)
// ---------------------------------------------------------------------------
__global__ void mix_kernel(const void* __restrict__ xraw,
                           const float* __restrict__ tmkF,
                           const float* __restrict__ tmvF,
                           const float* __restrict__ tmrF,
                           const int* __restrict__ flagp,
                           __bf16* __restrict__ xk,
                           __bf16* __restrict__ xv,
                           __bf16* __restrict__ xr)
{
  const int isf32 = *flagp;
  const int64_t NV = (int64_t)MM * DD / 8;
  for (int64_t v = blockIdx.x * (int64_t)blockDim.x + threadIdx.x;
       v < NV; v += (int64_t)gridDim.x * blockDim.x) {
    const int64_t i = v * 8;
    const int d = (int)(i & (DD - 1));
    const int64_t td = i & ((int64_t)TT * DD - 1);
    const bool has_prev = (td >= DD);
    float xc[8], xp[8];
    if (isf32) {
      const float* xf = (const float*)xraw;
      f32x4 a = *(const f32x4*)(xf + i);
      f32x4 b = *(const f32x4*)(xf + i + 4);
      #pragma unroll
      for (int e = 0; e < 4; e++) { xc[e] = a[e]; xc[e+4] = b[e]; }
      if (has_prev) {
        f32x4 c = *(const f32x4*)(xf + i - DD);
        f32x4 dd4 = *(const f32x4*)(xf + i - DD + 4);
        #pragma unroll
        for (int e = 0; e < 4; e++) { xp[e] = c[e]; xp[e+4] = dd4[e]; }
      } else {
        #pragma unroll
        for (int e = 0; e < 8; e++) xp[e] = 0.f;
      }
    } else {
      const __bf16* xb = (const __bf16*)xraw;
      bf16x8 a = *(const bf16x8*)(xb + i);
      #pragma unroll
      for (int e = 0; e < 8; e++) xc[e] = (float)a[e];
      if (has_prev) {
        bf16x8 c = *(const bf16x8*)(xb + i - DD);
        #pragma unroll
        for (int e = 0; e < 8; e++) xp[e] = (float)c[e];
      } else {
        #pragma unroll
        for (int e = 0; e < 8; e++) xp[e] = 0.f;
      }
    }
    bf16x8 ok, ov, orr;
    #pragma unroll
    for (int e = 0; e < 8; e++) {
      const float diff = xc[e] - xp[e];
      ok[e]  = (__bf16)(xp[e] + tmkF[d + e] * diff);
      ov[e]  = (__bf16)(xp[e] + tmvF[d + e] * diff);
      orr[e] = (__bf16)(xp[e] + tmrF[d + e] * diff);
    }
    *(bf16x8*)(xk + i) = ok;
    *(bf16x8*)(xv + i) = ov;
    *(bf16x8*)(xr + i) = orr;
  }
}

// ---------------------------------------------------------------------------
// Kernel 2: GEMM (r10 verbatim — best measured: 163us, occ 40%, 0 conflicts,
// no spill). 128x256 tile, 8 waves (2Mx4N, 64x64/wave -> acc 64 regs), BK=32,
// double-buffered 48 KiB LDS, launch_bounds(512,4) -> 2 blocks/CU, 4 waves/
// SIMD from independent blocks. r6 swizzle (chunk^((row>>1)&3), 0-conflict),
// r8 A-reuse XCD map (A-panel sharers co-resident on one XCD's L2), counted
// vmcnt (never 0 in-loop), derived waits (2 barriers/tile), setprio.
// EPI: 0=f32, 1=final(flag?f32:bf16), 2=sigmoid->bf16, 3=bf16.
// ---------------------------------------------------------------------------
#define BARX()   __builtin_amdgcn_s_barrier()
#define SCHEDB() __builtin_amdgcn_sched_barrier(0)
#define WAITL(n) asm volatile("s_waitcnt lgkmcnt(" #n ")" ::: "memory")
#define WAITV(n) asm volatile("s_waitcnt vmcnt(" #n ")" ::: "memory")

// stage K-tile kt: A = 128 rows (1 g2l/thread), B = 256 rows (2 g2l/thread)
#define STG_A(PB, kt) \
    g2l16(Asrc + (size_t)(kt)*32, smem + (PB) + tid*8)
#define STG_B(PB, kt) do { \
    g2l16(Bsrc + (size_t)(kt)*32,                 smem + (PB) + 4096 + tid*8); \
    g2l16(Bsrc + (size_t)128*Kd + (size_t)(kt)*32, smem + (PB) + 8192 + tid*8); \
  } while (0)

#define RD_A(pb) do { _Pragma("unroll") for (int i_ = 0; i_ < 4; i_++) \
    af[i_] = *(const bf16x8*)(smem + (pb) + aoff + i_*512); } while (0)
#define RD_B(pb) do { _Pragma("unroll") for (int j_ = 0; j_ < 4; j_++) \
    bfr[j_] = *(const bf16x8*)(smem + (pb) + boff + j_*512); } while (0)

#define MFMA_J(J) do { _Pragma("unroll") for (int i_ = 0; i_ < 4; i_++) \
    acc[i_][J] = __builtin_amdgcn_mfma_f32_16x16x32_bf16(af[i_], bfr[J], acc[i_][J], 0, 0, 0); } while (0)

#define TILE32(CB, OB, tA, tB) do { \
    RD_A(CB); RD_B(CB); \
    STG_A(OB, tA); \
    __builtin_amdgcn_s_setprio(1); \
    MFMA_J(0); MFMA_J(1); \
    __builtin_amdgcn_s_setprio(0); \
    WAITL(0); \
    BARX(); \
    SCHEDB(); \
    STG_B(CB, tB); \
    __builtin_amdgcn_s_setprio(1); \
    MFMA_J(2); MFMA_J(3); \
    __builtin_amdgcn_s_setprio(0); \
    WAITV(2); \
    BARX(); \
    SCHEDB(); \
  } while (0)

template <int EPI>
__global__ void __launch_bounds__(512, 4)
gemm_bt(const __bf16* __restrict__ A,
        const __bf16* __restrict__ Bm,
        void* __restrict__ Cout,
        const int* __restrict__ flagp,
        int Md, int Nd, int Kd)
{
  __shared__ __bf16 smem[24576];   // 48 KiB -> 2 blocks/CU
  const int isf32 = (EPI == 1) ? *flagp : 0;
  const int tid  = threadIdx.x;    // 0..511
  const int lane = tid & 63;
  const int wv   = tid >> 6;       // 0..7
  const int wm   = wv >> 2;        // wave row 0..1 (64 rows each)
  const int wn   = wv & 3;         // wave col 0..3 (64 cols each)
  const int l16  = lane & 15;
  const int qd   = lane >> 4;

  // A-reuse XCD map (r8): the 8 colblk-sharers of one A panel are stride-8
  // in bid -> same XCD.
  const int bid    = blockIdx.x;          // 0..1023
  const int xcd    = bid & 7;
  const int colblk = (bid >> 3) & 7;
  const int rowsub = bid >> 6;            // 0..15
  const int row0   = (xcd * 16 + rowsub) * 128;
  const int col0   = colblk * 256;

  // staging: thread -> row tid>>2 (0..127), phys chunk tid&3; global chunk
  // inverse-swizzled with row bits [2:1] (r6 pattern, 0 conflicts measured).
  const int srow   = tid >> 2;
  const int schunk = (tid & 3) ^ ((srow >> 1) & 3);
  const __bf16* Asrc = A  + (size_t)(row0 + srow) * Kd + schunk * 8;
  const __bf16* Bsrc = Bm + (size_t)(col0 + srow) * Kd + schunk * 8;

  // ds_read: fragment row = w*64 + f*16 + l16 -> (row>>1)&3 == (l16>>1)&3
  const int c0   = (qd ^ ((l16 >> 1) & 3)) * 8;
  const int aoff = (wm * 64 + l16) * 32 + c0;
  const int boff = 4096 + (wn * 64 + l16) * 32 + c0;

  f32x4 acc[4][4];
  #pragma unroll
  for (int i = 0; i < 4; i++)
    #pragma unroll
    for (int j = 0; j < 4; j++)
      acc[i][j] = (f32x4){0.f, 0.f, 0.f, 0.f};

  bf16x8 af[4], bfr[4];

  // Prologue: tile0 A+B -> buf0, tile1 B -> buf1. WAITV(2) drains A0,B0
  // (FIFO), leaves tile1.B (2) = steady-state invariant.
  STG_A(0, 0);
  STG_B(0, 0);
  STG_B(12288, 1);
  WAITV(2);
  BARX();
  SCHEDB();

  // 64 K-tiles. Main loop t=0..61 (stages A(1..62), B(2..63)); tail 62,63.
  #pragma unroll 1
  for (int it = 0; it < 31; ++it) {
    const int t = it << 1;
    TILE32(0,     12288, t + 1, t + 2);
    TILE32(12288, 0,     t + 2, t + 3);
  }

  // tile 62 (buf0): stage only A(63)->buf1 (B(63) staged at t=61); drain.
  {
    RD_A(0); RD_B(0);
    STG_A(12288, 63);
    __builtin_amdgcn_s_setprio(1);
    MFMA_J(0); MFMA_J(1); MFMA_J(2); MFMA_J(3);
    __builtin_amdgcn_s_setprio(0);
    WAITV(0);
    BARX();
    SCHEDB();
  }
  // tile 63 (buf1): no staging, no barriers.
  {
    RD_A(12288); RD_B(12288);
    __builtin_amdgcn_s_setprio(1);
    MFMA_J(0); MFMA_J(1); MFMA_J(2); MFMA_J(3);
    __builtin_amdgcn_s_setprio(0);
  }

  // epilogue: C/D layout col=lane&15, row=quad*4+reg (verified m89/m91)
  #pragma unroll
  for (int i = 0; i < 4; i++) {
    const int rb = row0 + wm * 64 + i * 16 + qd * 4;
    #pragma unroll
    for (int j = 0; j < 4; j++) {
      const int c = col0 + wn * 64 + j * 16 + l16;
      #pragma unroll
      for (int reg = 0; reg < 4; reg++) {
        const size_t idx = (size_t)(rb + reg) * Nd + c;
        float v = acc[i][j][reg];
        if (EPI == 0) {
          ((float*)Cout)[idx] = v;
        } else if (EPI == 1) {
          if (isf32) ((float*)Cout)[idx] = v;
          else       ((__bf16*)Cout)[idx] = (__bf16)v;
        } else if (EPI == 3) {
          ((__bf16*)Cout)[idx] = (__bf16)v;
        } else {
          float s = 1.f / (1.f + __expf(-v));
          ((__bf16*)Cout)[idx] = (__bf16)s;
        }
      }
    }
  }
}

// ---------------------------------------------------------------------------
// WKV parallel log-sum-exp prefix sum (r9 structure: part + scan + separate
// out, all 2-wide; fused variant reverted — it cost ~+50us from 64 serial
// block-wide reductions in only 256 blocks).
// ---------------------------------------------------------------------------
__global__ void wkv_part_kernel(const float* __restrict__ Kb,
                                const __bf16* __restrict__ Vb,
                                float* __restrict__ pM,
                                float* __restrict__ pA,
                                float* __restrict__ pB)
{
  const int gid = blockIdx.x * blockDim.x + threadIdx.x;  // 0..B*WC*D/2-1
  const int d = (gid & (DD / 2 - 1)) * 2;
  const int rest = gid >> 10;
  const int c = rest & (WC - 1);
  const int b = rest >> 6;
  const float*  kp = Kb + ((size_t)b * TT + (size_t)c * WL) * DD + d;
  const __bf16* vp = Vb + ((size_t)b * TT + (size_t)c * WL) * DD + d;
  float M0 = -1e38f, A0 = 0.f, B0 = 0.f;
  float M1 = -1e38f, A1 = 0.f, B1 = 0.f;
  for (int t = 0; t < WL; t++) {
    const float2 k2 = *(const float2*)(kp + (size_t)t * DD);
    const bf16x2 v2 = *(const bf16x2*)(vp + (size_t)t * DD);
    {
      const float q = fmaxf(M0, k2.x);
      const float s = __expf(M0 - q);
      const float e = __expf(k2.x - q);
      A0 = A0 * s + e * (float)v2[0];
      B0 = B0 * s + e;
      M0 = q;
    }
    {
      const float q = fmaxf(M1, k2.y);
      const float s = __expf(M1 - q);
      const float e = __expf(k2.y - q);
      A1 = A1 * s + e * (float)v2[1];
      B1 = B1 * s + e;
      M1 = q;
    }
  }
  const size_t pi = ((size_t)b * WC + c) * DD + d;
  *(float2*)(pM + pi) = make_float2(M0, M1);
  *(float2*)(pA + pi) = make_float2(A0, A1);
  *(float2*)(pB + pi) = make_float2(B0, B1);
}

__global__ void wkv_scan_kernel(float* __restrict__ pM,
                                float* __restrict__ pA,
                                float* __restrict__ pB)
{
  const int gid = blockIdx.x * blockDim.x + threadIdx.x;  // 0..B*D/2-1
  const int d = (gid & (DD / 2 - 1)) * 2;
  const int b = gid >> 10;
  float M0 = -1e38f, A0 = 0.f, B0 = 0.f;
  float M1 = -1e38f, A1 = 0.f, B1 = 0.f;
  for (int c = 0; c < WC; c++) {
    const size_t pi = ((size_t)b * WC + c) * DD + d;
    const float2 m2 = *(const float2*)(pM + pi);
    const float2 a2 = *(const float2*)(pA + pi);
    const float2 b2 = *(const float2*)(pB + pi);
    *(float2*)(pM + pi) = make_float2(M0, M1);
    *(float2*)(pA + pi) = make_float2(A0, A1);
    *(float2*)(pB + pi) = make_float2(B0, B1);
    {
      const float q = fmaxf(M0, m2.x);
      const float s0 = __expf(M0 - q);
      const float s1 = __expf(m2.x - q);
      A0 = A0 * s0 + a2.x * s1;
      B0 = B0 * s0 + b2.x * s1;
      M0 = q;
    }
    {
      const float q = fmaxf(M1, m2.y);
      const float s0 = __expf(M1 - q);
      const float s1 = __expf(m2.y - q);
      A1 = A1 * s0 + a2.y * s1;
      B1 = B1 * s0 + b2.y * s1;
      M1 = q;
    }
  }
}

__global__ void wkv_out_kernel(const float* __restrict__ Kb,
                               const __bf16* __restrict__ Vb,
                               const float* __restrict__ pM,
                               const float* __restrict__ pA,
                               const float* __restrict__ pB,
                               const float* __restrict__ tfirstF,
                               __bf16* __restrict__ out)
{
  const int gid = blockIdx.x * blockDim.x + threadIdx.x;
  const int d = (gid & (DD / 2 - 1)) * 2;
  const int rest = gid >> 10;
  const int c = rest & (WC - 1);
  const int b = rest >> 6;
  const size_t pi = ((size_t)b * WC + c) * DD + d;
  float2 M2 = *(const float2*)(pM + pi);
  float2 A2 = *(const float2*)(pA + pi);
  float2 B2 = *(const float2*)(pB + pi);
  float M0 = M2.x, A0 = A2.x, B0 = B2.x;
  float M1 = M2.y, A1 = A2.y, B1 = B2.y;
  const float u0 = tfirstF[d];
  const float u1 = tfirstF[d + 1];
  const size_t base = ((size_t)b * TT + (size_t)c * WL) * DD + d;
  const float*  kp = Kb + base;
  const __bf16* vp = Vb + base;
  __bf16*       op = out + base;
  for (int t = 0; t < WL; t++) {
    const float2 k2 = *(const float2*)(kp + (size_t)t * DD);
    const bf16x2 v2 = *(const bf16x2*)(vp + (size_t)t * DD);
    bf16x2 o2;
    {
      const float v = (float)v2[0];
      const float ku = k2.x + u0;
      const float qo = fmaxf(M0, ku);
      const float so = __expf(M0 - qo);
      const float eo = __expf(ku - qo);
      o2[0] = (__bf16)__fdividef(A0 * so + v * eo, B0 * so + eo);
      const float q = fmaxf(M0, k2.x);
      const float s = __expf(M0 - q);
      const float e = __expf(k2.x - q);
      A0 = A0 * s + e * v;
      B0 = B0 * s + e;
      M0 = q;
    }
    {
      const float v = (float)v2[1];
      const float ku = k2.y + u1;
      const float qo = fmaxf(M1, ku);
      const float so = __expf(M1 - qo);
      const float eo = __expf(ku - qo);
      o2[1] = (__bf16)__fdividef(A1 * so + v * eo, B1 * so + eo);
      const float q = fmaxf(M1, k2.y);
      const float s = __expf(M1 - q);
      const float e = __expf(k2.y - q);
      A1 = A1 * s + e * v;
      B1 = B1 * s + e;
      M1 = q;
    }
    *(bf16x2*)(op + (size_t)t * DD) = o2;
  }
}

// ---------------------------------------------------------------------------
// Kernel 4: LayerNorm over D + multiply by r -> rwkv (bf16). r9 version:
// bf16 wkv input, 8-consecutive-element vectorized loads/stores (16 B/lane).
// ---------------------------------------------------------------------------
__global__ void ln_kernel(const __bf16* __restrict__ wkv,
                          const __bf16* __restrict__ rbuf,
                          const float* __restrict__ g,
                          const float* __restrict__ beta,
                          __bf16* __restrict__ out)
{
  const int row = blockIdx.x;
  const int tid = threadIdx.x;
  const size_t base = (size_t)row * DD + (size_t)tid * 8;

  bf16x8 w8 = *(const bf16x8*)(wkv + base);
  float vals[8];
  float s = 0.f, sq = 0.f;
  #pragma unroll
  for (int e = 0; e < 8; e++) {
    const float v = (float)w8[e];
    vals[e] = v;
    s += v;
    sq += v * v;
  }
  #pragma unroll
  for (int off = 1; off < 64; off <<= 1) {
    s  += __shfl_xor(s, off);
    sq += __shfl_xor(sq, off);
  }
  __shared__ float ls[4], lsq[4];
  const int wave = tid >> 6;
  if ((tid & 63) == 0) { ls[wave] = s; lsq[wave] = sq; }
  __syncthreads();
  s  = ls[0] + ls[1] + ls[2] + ls[3];
  sq = lsq[0] + lsq[1] + lsq[2] + lsq[3];

  const float mu = s * (1.f / DD);
  const float var = sq * (1.f / DD) - mu * mu;
  const float rs = rsqrtf(var + 1e-5f);

  bf16x8 r8 = *(const bf16x8*)(rbuf + base);
  f32x4 g0 = *(const f32x4*)(g + tid * 8);
  f32x4 g1 = *(const f32x4*)(g + tid * 8 + 4);
  f32x4 be0 = *(const f32x4*)(beta + tid * 8);
  f32x4 be1 = *(const f32x4*)(beta + tid * 8 + 4);

  bf16x8 o8;
  #pragma unroll
  for (int e = 0; e < 4; e++) {
    const float v0 = (vals[e] - mu) * rs * g0[e] + be0[e];
    const float v1 = (vals[e + 4] - mu) * rs * g1[e] + be1[e];
    o8[e]     = (__bf16)((float)r8[e]     * v0);
    o8[e + 4] = (__bf16)((float)r8[e + 4] * v1);
  }
  *(bf16x8*)(out + base) = o8;
}

// ---------------------------------------------------------------------------
extern "C" void kernel_launch(void* const* d_in, const int* in_sizes, int n_in,
                              void* d_out, int out_size, void* d_ws, size_t ws_size,
                              hipStream_t stream) {
  const void* x      = d_in[0];
  const void* Wk     = d_in[1];
  const void* Wv     = d_in[2];
  const void* Wr     = d_in[3];
  const void* Wo     = d_in[4];
  const void* tmk    = d_in[5];
  const void* tmv    = d_in[6];
  const void* tmr    = d_in[7];
  const void* tdec   = d_in[8];
  const void* tfirst = d_in[9];
  const void* lng    = d_in[10];
  const void* lnb    = d_in[11];

  char* ws = (char*)d_ws;
  const size_t SZ_BF = (size_t)MM * DD * 2;   // 64 MiB
  const size_t SZ_F  = (size_t)MM * DD * 4;   // 128 MiB
  const size_t SZ_W  = (size_t)DD * DD * 2;   // 8 MiB
  __bf16* XK   = (__bf16*)(ws);
  __bf16* XV   = (__bf16*)(ws + SZ_BF);
  __bf16* XR   = (__bf16*)(ws + 2 * SZ_BF);
  float*  Kb   = (float*)(ws + 3 * SZ_BF);
  char*   VbSlot = ws + 3 * SZ_BF + SZ_F;            // 128 MiB slot
  __bf16* Vb   = (__bf16*)VbSlot;                    // bf16: first 64 MiB
  // prefix arrays in the free upper half of the Vb slot (no aliasing with
  // Wkv / Rwkv regions).
  float* pM = (float*)(VbSlot + SZ_BF);
  float* pA = pM + (size_t)BB * WC * DD;
  float* pB = pA + (size_t)BB * WC * DD;
  __bf16* WkB  = (__bf16*)(ws + 3 * SZ_BF + 2 * SZ_F);
  __bf16* WvB  = (__bf16*)(ws + 3 * SZ_BF + 2 * SZ_F + SZ_W);
  __bf16* WrB  = (__bf16*)(ws + 3 * SZ_BF + 2 * SZ_F + 2 * SZ_W);
  __bf16* WoB  = (__bf16*)(ws + 3 * SZ_BF + 2 * SZ_F + 3 * SZ_W);
  char*   smal = ws + 3 * SZ_BF + 2 * SZ_F + 4 * SZ_W;
  int*    flag    = (int*)smal;
  float*  tdecF   = (float*)(smal + 64);
  float*  tfirstF = tdecF + DD;
  float*  lngF    = tdecF + 2 * DD;
  float*  lnbF    = tdecF + 3 * DD;
  float*  tmkF    = tdecF + 4 * DD;
  float*  tmvF    = tdecF + 5 * DD;
  float*  tmrF    = tdecF + 6 * DD;
  __bf16* Wkv  = (__bf16*)(ws);                // bf16; over XK (dead after GEMMs)
  __bf16* Rwkv = (__bf16*)(ws + 2 * SZ_BF);    // over XR (dead after R-GEMM)
  __bf16* Rb   = (__bf16*)d_out;               // d_out as scratch until final GEMM

  detect_small_kernel<<<dim3(1), dim3(256), 0, stream>>>(
      tdec, tfirst, lng, lnb, tmk, tmv, tmr,
      flag, tdecF, tfirstF, lngF, lnbF, tmkF, tmvF, tmrF);

  convert_w_kernel<<<dim3(512), dim3(256), 0, stream>>>(Wk, WkB, flag);
  convert_w_kernel<<<dim3(512), dim3(256), 0, stream>>>(Wv, WvB, flag);
  convert_w_kernel<<<dim3(512), dim3(256), 0, stream>>>(Wr, WrB, flag);
  convert_w_kernel<<<dim3(512), dim3(256), 0, stream>>>(Wo, WoB, flag);

  mix_kernel<<<dim3(4096), dim3(256), 0, stream>>>(x, tmkF, tmvF, tmrF, flag, XK, XV, XR);

  // 128x256 tiles: (16384/128)*(2048/256) = 128*8 = 1024 blocks, 512 thr
  dim3 g(1024), blk(512);
  gemm_bt<0><<<g, blk, 0, stream>>>(XK, WkB, (void*)Kb, flag, MM, DD, DD);
  gemm_bt<3><<<g, blk, 0, stream>>>(XV, WvB, (void*)Vb, flag, MM, DD, DD);
  gemm_bt<2><<<g, blk, 0, stream>>>(XR, WrB, (void*)Rb, flag, MM, DD, DD);

  // 2-wide wkv: B*WC*D/2 = 262144 threads -> 1024 blocks; scan 16 blocks
  wkv_part_kernel<<<dim3(1024), dim3(256), 0, stream>>>(Kb, Vb, pM, pA, pB);
  wkv_scan_kernel<<<dim3(16), dim3(256), 0, stream>>>(pM, pA, pB);
  wkv_out_kernel<<<dim3(1024), dim3(256), 0, stream>>>(Kb, Vb, pM, pA, pB, tfirstF, Wkv);

  ln_kernel<<<dim3(MM), dim3(256), 0, stream>>>(Wkv, Rb, lngF, lnbF, Rwkv);

  gemm_bt<1><<<g, blk, 0, stream>>>(Rwkv, WoB, d_out, flag, MM, DD, DD);
}

// Round 12
// 858.961 us; speedup vs baseline: 1.0651x; 1.0256x over previous
//
#include <hip/hip_runtime.h>
#include <hip/hip_bf16.h>
#include <stdint.h>

// Problem constants
#define BB 4
#define TT 4096
#define DD 2048
#define MM (BB*TT)   // 16384 rows
#define WC 64        // wkv chunks per sequence
#define WL 64        // wkv chunk length (WC*WL == TT)

typedef __bf16 bf16x8 __attribute__((ext_vector_type(8)));
typedef __bf16 bf16x4 __attribute__((ext_vector_type(4)));
typedef __bf16 bf16x2 __attribute__((ext_vector_type(2)));
typedef float  f32x4  __attribute__((ext_vector_type(4)));

__device__ __forceinline__ void g2l16(const void* g, void* l) {
  __builtin_amdgcn_global_load_lds(
      (const __attribute__((address_space(1))) void*)g,
      (__attribute__((address_space(3))) void*)l,
      16, 0, 0);
}

// ---------------------------------------------------------------------------
// Kernel 0: dtype detect + convert small vectors to fp32.
// ---------------------------------------------------------------------------
__global__ void detect_small_kernel(const void* __restrict__ tdec_raw,
                                    const void* __restrict__ tfirst_raw,
                                    const void* __restrict__ lng_raw,
                                    const void* __restrict__ lnb_raw,
                                    const void* __restrict__ tmk_raw,
                                    const void* __restrict__ tmv_raw,
                                    const void* __restrict__ tmr_raw,
                                    int* __restrict__ flag,
                                    float* __restrict__ tdecF,
                                    float* __restrict__ tfirstF,
                                    float* __restrict__ lngF,
                                    float* __restrict__ lnbF,
                                    float* __restrict__ tmkF,
                                    float* __restrict__ tmvF,
                                    float* __restrict__ tmrF)
{
  const uint32_t w0 = *(const uint32_t*)tdec_raw;
  const int isf32 = ((w0 & 0xFFFFu) == 0u) ? 1 : 0;
  if (threadIdx.x == 0) *flag = isf32;
  for (int d = threadIdx.x; d < DD; d += blockDim.x) {
    if (isf32) {
      tdecF[d]   = ((const float*)tdec_raw)[d];
      tfirstF[d] = ((const float*)tfirst_raw)[d];
      lngF[d]    = ((const float*)lng_raw)[d];
      lnbF[d]    = ((const float*)lnb_raw)[d];
      tmkF[d]    = ((const float*)tmk_raw)[d];
      tmvF[d]    = ((const float*)tmv_raw)[d];
      tmrF[d]    = ((const float*)tmr_raw)[d];
    } else {
      tdecF[d]   = (float)((const __bf16*)tdec_raw)[d];
      tfirstF[d] = (float)((const __bf16*)tfirst_raw)[d];
      lngF[d]    = (float)((const __bf16*)lng_raw)[d];
      lnbF[d]    = (float)((const __bf16*)lnb_raw)[d];
      tmkF[d]    = (float)((const __bf16*)tmk_raw)[d];
      tmvF[d]    = (float)((const __bf16*)tmv_raw)[d];
      tmrF[d]    = (float)((const __bf16*)tmr_raw)[d];
    }
  }
}

// ---------------------------------------------------------------------------
// Kernel 0b: convert one DxD weight matrix to canonical bf16
// ---------------------------------------------------------------------------
__global__ void convert_w_kernel(const void* __restrict__ src,
                                 __bf16* __restrict__ dst,
                                 const int* __restrict__ flagp)
{
  const int isf32 = *flagp;
  const int64_t NV = (int64_t)DD * DD / 8;
  for (int64_t v = blockIdx.x * (int64_t)blockDim.x + threadIdx.x;
       v < NV; v += (int64_t)gridDim.x * blockDim.x) {
    const int64_t i = v * 8;
    bf16x8 o;
    if (isf32) {
      const float* sf = (const float*)src;
      f32x4 a = *(const f32x4*)(sf + i);
      f32x4 b = *(const f32x4*)(sf + i + 4);
      #pragma unroll
      for (int e = 0; e < 4; e++) { o[e] = (__bf16)a[e]; o[e+4] = (__bf16)b[e]; }
    } else {
      o = *(const bf16x8*)((const __bf16*)src + i);
    }
    *(bf16x8*)(dst + i) = o;
  }
}

// ---------------------------------------------------------------------------
// Kernel 1: token-shift mix -> xk, xv, xr (bf16)
// ---------------------------------------------------------------------------
__global__ void mix_kernel(const void* __restrict__ xraw,
                           const float* __restrict__ tmkF,
                           const float* __restrict__ tmvF,
                           const float* __restrict__ tmrF,
                           const int* __restrict__ flagp,
                           __bf16* __restrict__ xk,
                           __bf16* __restrict__ xv,
                           __bf16* __restrict__ xr)
{
  const int isf32 = *flagp;
  const int64_t NV = (int64_t)MM * DD / 8;
  for (int64_t v = blockIdx.x * (int64_t)blockDim.x + threadIdx.x;
       v < NV; v += (int64_t)gridDim.x * blockDim.x) {
    const int64_t i = v * 8;
    const int d = (int)(i & (DD - 1));
    const int64_t td = i & ((int64_t)TT * DD - 1);
    const bool has_prev = (td >= DD);
    float xc[8], xp[8];
    if (isf32) {
      const float* xf = (const float*)xraw;
      f32x4 a = *(const f32x4*)(xf + i);
      f32x4 b = *(const f32x4*)(xf + i + 4);
      #pragma unroll
      for (int e = 0; e < 4; e++) { xc[e] = a[e]; xc[e+4] = b[e]; }
      if (has_prev) {
        f32x4 c = *(const f32x4*)(xf + i - DD);
        f32x4 dd4 = *(const f32x4*)(xf + i - DD + 4);
        #pragma unroll
        for (int e = 0; e < 4; e++) { xp[e] = c[e]; xp[e+4] = dd4[e]; }
      } else {
        #pragma unroll
        for (int e = 0; e < 8; e++) xp[e] = 0.f;
      }
    } else {
      const __bf16* xb = (const __bf16*)xraw;
      bf16x8 a = *(const bf16x8*)(xb + i);
      #pragma unroll
      for (int e = 0; e < 8; e++) xc[e] = (float)a[e];
      if (has_prev) {
        bf16x8 c = *(const bf16x8*)(xb + i - DD);
        #pragma unroll
        for (int e = 0; e < 8; e++) xp[e] = (float)c[e];
      } else {
        #pragma unroll
        for (int e = 0; e < 8; e++) xp[e] = 0.f;
      }
    }
    bf16x8 ok, ov, orr;
    #pragma unroll
    for (int e = 0; e < 8; e++) {
      const float diff = xc[e] - xp[e];
      ok[e]  = (__bf16)(xp[e] + tmkF[d + e] * diff);
      ov[e]  = (__bf16)(xp[e] + tmvF[d + e] * diff);
      orr[e] = (__bf16)(xp[e] + tmrF[d + e] * diff);
    }
    *(bf16x8*)(xk + i) = ok;
    *(bf16x8*)(xv + i) = ov;
    *(bf16x8*)(xr + i) = orr;
  }
}

// ---------------------------------------------------------------------------
// Kernel 2: GEMM (r10/r11 verbatim — 163us, occ 40%, LDS-read-pipe bound:
// 1528 cyc/tile measured == 1536 model [128 ds_read_b128 x 12cyc per
// 2-block tile-instance]; MFMA needs 1280. Bigger per-wave tiles would cut
// LDS bytes/FLOP but break the <=128-reg 2-block budget -> frozen.)
// 128x256 tile, 8 waves (64x64/wave, acc 64 regs), BK=32, dbuf 48 KiB LDS,
// launch_bounds(512,4) -> 2 blocks/CU. r6 swizzle, r8 A-reuse XCD map,
// counted vmcnt, derived waits, setprio.
// EPI: 0=f32, 1=final(flag?f32:bf16), 2=sigmoid->bf16, 3=bf16.
// ---------------------------------------------------------------------------
#define BARX()   __builtin_amdgcn_s_barrier()
#define SCHEDB() __builtin_amdgcn_sched_barrier(0)
#define WAITL(n) asm volatile("s_waitcnt lgkmcnt(" #n ")" ::: "memory")
#define WAITV(n) asm volatile("s_waitcnt vmcnt(" #n ")" ::: "memory")

// stage K-tile kt: A = 128 rows (1 g2l/thread), B = 256 rows (2 g2l/thread)
#define STG_A(PB, kt) \
    g2l16(Asrc + (size_t)(kt)*32, smem + (PB) + tid*8)
#define STG_B(PB, kt) do { \
    g2l16(Bsrc + (size_t)(kt)*32,                 smem + (PB) + 4096 + tid*8); \
    g2l16(Bsrc + (size_t)128*Kd + (size_t)(kt)*32, smem + (PB) + 8192 + tid*8); \
  } while (0)

#define RD_A(pb) do { _Pragma("unroll") for (int i_ = 0; i_ < 4; i_++) \
    af[i_] = *(const bf16x8*)(smem + (pb) + aoff + i_*512); } while (0)
#define RD_B(pb) do { _Pragma("unroll") for (int j_ = 0; j_ < 4; j_++) \
    bfr[j_] = *(const bf16x8*)(smem + (pb) + boff + j_*512); } while (0)

#define MFMA_J(J) do { _Pragma("unroll") for (int i_ = 0; i_ < 4; i_++) \
    acc[i_][J] = __builtin_amdgcn_mfma_f32_16x16x32_bf16(af[i_], bfr[J], acc[i_][J], 0, 0, 0); } while (0)

#define TILE32(CB, OB, tA, tB) do { \
    RD_A(CB); RD_B(CB); \
    STG_A(OB, tA); \
    __builtin_amdgcn_s_setprio(1); \
    MFMA_J(0); MFMA_J(1); \
    __builtin_amdgcn_s_setprio(0); \
    WAITL(0); \
    BARX(); \
    SCHEDB(); \
    STG_B(CB, tB); \
    __builtin_amdgcn_s_setprio(1); \
    MFMA_J(2); MFMA_J(3); \
    __builtin_amdgcn_s_setprio(0); \
    WAITV(2); \
    BARX(); \
    SCHEDB(); \
  } while (0)

template <int EPI>
__global__ void __launch_bounds__(512, 4)
gemm_bt(const __bf16* __restrict__ A,
        const __bf16* __restrict__ Bm,
        void* __restrict__ Cout,
        const int* __restrict__ flagp,
        int Md, int Nd, int Kd)
{
  __shared__ __bf16 smem[24576];   // 48 KiB -> 2 blocks/CU
  const int isf32 = (EPI == 1) ? *flagp : 0;
  const int tid  = threadIdx.x;    // 0..511
  const int lane = tid & 63;
  const int wv   = tid >> 6;       // 0..7
  const int wm   = wv >> 2;        // wave row 0..1 (64 rows each)
  const int wn   = wv & 3;         // wave col 0..3 (64 cols each)
  const int l16  = lane & 15;
  const int qd   = lane >> 4;

  // A-reuse XCD map (r8): the 8 colblk-sharers of one A panel are stride-8
  // in bid -> same XCD.
  const int bid    = blockIdx.x;          // 0..1023
  const int xcd    = bid & 7;
  const int colblk = (bid >> 3) & 7;
  const int rowsub = bid >> 6;            // 0..15
  const int row0   = (xcd * 16 + rowsub) * 128;
  const int col0   = colblk * 256;

  // staging: thread -> row tid>>2 (0..127), phys chunk tid&3; global chunk
  // inverse-swizzled with row bits [2:1] (r6 pattern, 0 conflicts measured).
  const int srow   = tid >> 2;
  const int schunk = (tid & 3) ^ ((srow >> 1) & 3);
  const __bf16* Asrc = A  + (size_t)(row0 + srow) * Kd + schunk * 8;
  const __bf16* Bsrc = Bm + (size_t)(col0 + srow) * Kd + schunk * 8;

  // ds_read: fragment row = w*64 + f*16 + l16 -> (row>>1)&3 == (l16>>1)&3
  const int c0   = (qd ^ ((l16 >> 1) & 3)) * 8;
  const int aoff = (wm * 64 + l16) * 32 + c0;
  const int boff = 4096 + (wn * 64 + l16) * 32 + c0;

  f32x4 acc[4][4];
  #pragma unroll
  for (int i = 0; i < 4; i++)
    #pragma unroll
    for (int j = 0; j < 4; j++)
      acc[i][j] = (f32x4){0.f, 0.f, 0.f, 0.f};

  bf16x8 af[4], bfr[4];

  // Prologue: tile0 A+B -> buf0, tile1 B -> buf1. WAITV(2) drains A0,B0
  // (FIFO), leaves tile1.B (2) = steady-state invariant.
  STG_A(0, 0);
  STG_B(0, 0);
  STG_B(12288, 1);
  WAITV(2);
  BARX();
  SCHEDB();

  // 64 K-tiles. Main loop t=0..61 (stages A(1..62), B(2..63)); tail 62,63.
  #pragma unroll 1
  for (int it = 0; it < 31; ++it) {
    const int t = it << 1;
    TILE32(0,     12288, t + 1, t + 2);
    TILE32(12288, 0,     t + 2, t + 3);
  }

  // tile 62 (buf0): stage only A(63)->buf1 (B(63) staged at t=61); drain.
  {
    RD_A(0); RD_B(0);
    STG_A(12288, 63);
    __builtin_amdgcn_s_setprio(1);
    MFMA_J(0); MFMA_J(1); MFMA_J(2); MFMA_J(3);
    __builtin_amdgcn_s_setprio(0);
    WAITV(0);
    BARX();
    SCHEDB();
  }
  // tile 63 (buf1): no staging, no barriers.
  {
    RD_A(12288); RD_B(12288);
    __builtin_amdgcn_s_setprio(1);
    MFMA_J(0); MFMA_J(1); MFMA_J(2); MFMA_J(3);
    __builtin_amdgcn_s_setprio(0);
  }

  // epilogue: C/D layout col=lane&15, row=quad*4+reg (verified m89/m91)
  #pragma unroll
  for (int i = 0; i < 4; i++) {
    const int rb = row0 + wm * 64 + i * 16 + qd * 4;
    #pragma unroll
    for (int j = 0; j < 4; j++) {
      const int c = col0 + wn * 64 + j * 16 + l16;
      #pragma unroll
      for (int reg = 0; reg < 4; reg++) {
        const size_t idx = (size_t)(rb + reg) * Nd + c;
        float v = acc[i][j][reg];
        if (EPI == 0) {
          ((float*)Cout)[idx] = v;
        } else if (EPI == 1) {
          if (isf32) ((float*)Cout)[idx] = v;
          else       ((__bf16*)Cout)[idx] = (__bf16)v;
        } else if (EPI == 3) {
          ((__bf16*)Cout)[idx] = (__bf16)v;
        } else {
          float s = 1.f / (1.f + __expf(-v));
          ((__bf16*)Cout)[idx] = (__bf16)s;
        }
      }
    }
  }
}

// ---------------------------------------------------------------------------
// WKV parallel log-sum-exp prefix sum. Round 12: Kb is bf16 (K-GEMM EPI=3;
// ~0.2% weight perturbation, same magnitude as the absmax-neutral V-bf16
// change) and part/out are 4-WIDE (bf16x4 k+v = 16B/thread/t; f32x4 prefix
// I/O). K+V working set 128 MB -> fully L3-resident between passes.
// ---------------------------------------------------------------------------
__global__ void wkv_part_kernel(const __bf16* __restrict__ Kb,
                                const __bf16* __restrict__ Vb,
                                float* __restrict__ pM,
                                float* __restrict__ pA,
                                float* __restrict__ pB)
{
  const int gid = blockIdx.x * blockDim.x + threadIdx.x;  // 0..B*WC*D/4-1
  const int d = (gid & (DD / 4 - 1)) * 4;
  const int rest = gid >> 9;
  const int c = rest & (WC - 1);
  const int b = rest >> 6;
  const __bf16* kp = Kb + ((size_t)b * TT + (size_t)c * WL) * DD + d;
  const __bf16* vp = Vb + ((size_t)b * TT + (size_t)c * WL) * DD + d;
  float M0 = -1e38f, A0 = 0.f, B0 = 0.f;
  float M1 = -1e38f, A1 = 0.f, B1 = 0.f;
  float M2 = -1e38f, A2 = 0.f, B2 = 0.f;
  float M3 = -1e38f, A3 = 0.f, B3 = 0.f;
  #define PSTEP(Mv, Av, Bv2, kf, vf) do { \
      const float q = fmaxf(Mv, kf); \
      const float s = __expf(Mv - q); \
      const float e = __expf((kf) - q); \
      Av = Av * s + e * (vf); \
      Bv2 = Bv2 * s + e; \
      Mv = q; \
    } while (0)
  for (int t = 0; t < WL; t++) {
    const bf16x4 k4 = *(const bf16x4*)(kp + (size_t)t * DD);
    const bf16x4 v4 = *(const bf16x4*)(vp + (size_t)t * DD);
    PSTEP(M0, A0, B0, (float)k4[0], (float)v4[0]);
    PSTEP(M1, A1, B1, (float)k4[1], (float)v4[1]);
    PSTEP(M2, A2, B2, (float)k4[2], (float)v4[2]);
    PSTEP(M3, A3, B3, (float)k4[3], (float)v4[3]);
  }
  const size_t pi = ((size_t)b * WC + c) * DD + d;
  *(f32x4*)(pM + pi) = (f32x4){M0, M1, M2, M3};
  *(f32x4*)(pA + pi) = (f32x4){A0, A1, A2, A3};
  *(f32x4*)(pB + pi) = (f32x4){B0, B1, B2, B3};
}

__global__ void wkv_scan_kernel(float* __restrict__ pM,
                                float* __restrict__ pA,
                                float* __restrict__ pB)
{
  const int gid = blockIdx.x * blockDim.x + threadIdx.x;  // 0..B*D/2-1
  const int d = (gid & (DD / 2 - 1)) * 2;
  const int b = gid >> 10;
  float M0 = -1e38f, A0 = 0.f, B0 = 0.f;
  float M1 = -1e38f, A1 = 0.f, B1 = 0.f;
  for (int c = 0; c < WC; c++) {
    const size_t pi = ((size_t)b * WC + c) * DD + d;
    const float2 m2 = *(const float2*)(pM + pi);
    const float2 a2 = *(const float2*)(pA + pi);
    const float2 b2 = *(const float2*)(pB + pi);
    *(float2*)(pM + pi) = make_float2(M0, M1);
    *(float2*)(pA + pi) = make_float2(A0, A1);
    *(float2*)(pB + pi) = make_float2(B0, B1);
    {
      const float q = fmaxf(M0, m2.x);
      const float s0 = __expf(M0 - q);
      const float s1 = __expf(m2.x - q);
      A0 = A0 * s0 + a2.x * s1;
      B0 = B0 * s0 + b2.x * s1;
      M0 = q;
    }
    {
      const float q = fmaxf(M1, m2.y);
      const float s0 = __expf(M1 - q);
      const float s1 = __expf(m2.y - q);
      A1 = A1 * s0 + a2.y * s1;
      B1 = B1 * s0 + b2.y * s1;
      M1 = q;
    }
  }
}

__global__ void wkv_out_kernel(const __bf16* __restrict__ Kb,
                               const __bf16* __restrict__ Vb,
                               const float* __restrict__ pM,
                               const float* __restrict__ pA,
                               const float* __restrict__ pB,
                               const float* __restrict__ tfirstF,
                               __bf16* __restrict__ out)
{
  const int gid = blockIdx.x * blockDim.x + threadIdx.x;  // 0..B*WC*D/4-1
  const int d = (gid & (DD / 4 - 1)) * 4;
  const int rest = gid >> 9;
  const int c = rest & (WC - 1);
  const int b = rest >> 6;
  const size_t pi = ((size_t)b * WC + c) * DD + d;
  f32x4 M4 = *(const f32x4*)(pM + pi);
  f32x4 A4 = *(const f32x4*)(pA + pi);
  f32x4 B4 = *(const f32x4*)(pB + pi);
  float M0 = M4[0], A0 = A4[0], B0 = B4[0];
  float M1 = M4[1], A1 = A4[1], B1 = B4[1];
  float M2 = M4[2], A2 = A4[2], B2 = B4[2];
  float M3 = M4[3], A3 = A4[3], B3 = B4[3];
  const f32x4 u4 = *(const f32x4*)(tfirstF + d);
  const size_t base = ((size_t)b * TT + (size_t)c * WL) * DD + d;
  const __bf16* kp = Kb + base;
  const __bf16* vp = Vb + base;
  __bf16*       op = out + base;
  #define OSTEP(Mv, Av, Bv2, kf, vf, uf, oref) do { \
      const float ku = (kf) + (uf); \
      const float qo = fmaxf(Mv, ku); \
      const float so = __expf(Mv - qo); \
      const float eo = __expf(ku - qo); \
      oref = (__bf16)__fdividef(Av * so + (vf) * eo, Bv2 * so + eo); \
      const float q = fmaxf(Mv, kf); \
      const float s = __expf(Mv - q); \
      const float e = __expf((kf) - q); \
      Av = Av * s + e * (vf); \
      Bv2 = Bv2 * s + e; \
      Mv = q; \
    } while (0)
  for (int t = 0; t < WL; t++) {
    const bf16x4 k4 = *(const bf16x4*)(kp + (size_t)t * DD);
    const bf16x4 v4 = *(const bf16x4*)(vp + (size_t)t * DD);
    bf16x4 o4;
    OSTEP(M0, A0, B0, (float)k4[0], (float)v4[0], u4[0], o4[0]);
    OSTEP(M1, A1, B1, (float)k4[1], (float)v4[1], u4[1], o4[1]);
    OSTEP(M2, A2, B2, (float)k4[2], (float)v4[2], u4[2], o4[2]);
    OSTEP(M3, A3, B3, (float)k4[3], (float)v4[3], u4[3], o4[3]);
    *(bf16x4*)(op + (size_t)t * DD) = o4;
  }
}

// ---------------------------------------------------------------------------
// Kernel 4: LayerNorm over D + multiply by r -> rwkv (bf16). r9 version:
// bf16 wkv input, 8-consecutive-element vectorized loads/stores (16 B/lane).
// ---------------------------------------------------------------------------
__global__ void ln_kernel(const __bf16* __restrict__ wkv,
                          const __bf16* __restrict__ rbuf,
                          const float* __restrict__ g,
                          const float* __restrict__ beta,
                          __bf16* __restrict__ out)
{
  const int row = blockIdx.x;
  const int tid = threadIdx.x;
  const size_t base = (size_t)row * DD + (size_t)tid * 8;

  bf16x8 w8 = *(const bf16x8*)(wkv + base);
  float vals[8];
  float s = 0.f, sq = 0.f;
  #pragma unroll
  for (int e = 0; e < 8; e++) {
    const float v = (float)w8[e];
    vals[e] = v;
    s += v;
    sq += v * v;
  }
  #pragma unroll
  for (int off = 1; off < 64; off <<= 1) {
    s  += __shfl_xor(s, off);
    sq += __shfl_xor(sq, off);
  }
  __shared__ float ls[4], lsq[4];
  const int wave = tid >> 6;
  if ((tid & 63) == 0) { ls[wave] = s; lsq[wave] = sq; }
  __syncthreads();
  s  = ls[0] + ls[1] + ls[2] + ls[3];
  sq = lsq[0] + lsq[1] + lsq[2] + lsq[3];

  const float mu = s * (1.f / DD);
  const float var = sq * (1.f / DD) - mu * mu;
  const float rs = rsqrtf(var + 1e-5f);

  bf16x8 r8 = *(const bf16x8*)(rbuf + base);
  f32x4 g0 = *(const f32x4*)(g + tid * 8);
  f32x4 g1 = *(const f32x4*)(g + tid * 8 + 4);
  f32x4 be0 = *(const f32x4*)(beta + tid * 8);
  f32x4 be1 = *(const f32x4*)(beta + tid * 8 + 4);

  bf16x8 o8;
  #pragma unroll
  for (int e = 0; e < 4; e++) {
    const float v0 = (vals[e] - mu) * rs * g0[e] + be0[e];
    const float v1 = (vals[e + 4] - mu) * rs * g1[e] + be1[e];
    o8[e]     = (__bf16)((float)r8[e]     * v0);
    o8[e + 4] = (__bf16)((float)r8[e + 4] * v1);
  }
  *(bf16x8*)(out + base) = o8;
}

// ---------------------------------------------------------------------------
extern "C" void kernel_launch(void* const* d_in, const int* in_sizes, int n_in,
                              void* d_out, int out_size, void* d_ws, size_t ws_size,
                              hipStream_t stream) {
  const void* x      = d_in[0];
  const void* Wk     = d_in[1];
  const void* Wv     = d_in[2];
  const void* Wr     = d_in[3];
  const void* Wo     = d_in[4];
  const void* tmk    = d_in[5];
  const void* tmv    = d_in[6];
  const void* tmr    = d_in[7];
  const void* tdec   = d_in[8];
  const void* tfirst = d_in[9];
  const void* lng    = d_in[10];
  const void* lnb    = d_in[11];

  char* ws = (char*)d_ws;
  const size_t SZ_BF = (size_t)MM * DD * 2;   // 64 MiB
  const size_t SZ_F  = (size_t)MM * DD * 4;   // 128 MiB
  const size_t SZ_W  = (size_t)DD * DD * 2;   // 8 MiB
  __bf16* XK   = (__bf16*)(ws);
  __bf16* XV   = (__bf16*)(ws + SZ_BF);
  __bf16* XR   = (__bf16*)(ws + 2 * SZ_BF);
  __bf16* Kb   = (__bf16*)(ws + 3 * SZ_BF);          // bf16 now (slot is 128MB)
  char*   VbSlot = ws + 3 * SZ_BF + SZ_F;            // 128 MiB slot
  __bf16* Vb   = (__bf16*)VbSlot;                    // bf16: first 64 MiB
  // prefix arrays in the free upper half of the Vb slot (no aliasing with
  // Wkv / Rwkv regions).
  float* pM = (float*)(VbSlot + SZ_BF);
  float* pA = pM + (size_t)BB * WC * DD;
  float* pB = pA + (size_t)BB * WC * DD;
  __bf16* WkB  = (__bf16*)(ws + 3 * SZ_BF + 2 * SZ_F);
  __bf16* WvB  = (__bf16*)(ws + 3 * SZ_BF + 2 * SZ_F + SZ_W);
  __bf16* WrB  = (__bf16*)(ws + 3 * SZ_BF + 2 * SZ_F + 2 * SZ_W);
  __bf16* WoB  = (__bf16*)(ws + 3 * SZ_BF + 2 * SZ_F + 3 * SZ_W);
  char*   smal = ws + 3 * SZ_BF + 2 * SZ_F + 4 * SZ_W;
  int*    flag    = (int*)smal;
  float*  tdecF   = (float*)(smal + 64);
  float*  tfirstF = tdecF + DD;
  float*  lngF    = tdecF + 2 * DD;
  float*  lnbF    = tdecF + 3 * DD;
  float*  tmkF    = tdecF + 4 * DD;
  float*  tmvF    = tdecF + 5 * DD;
  float*  tmrF    = tdecF + 6 * DD;
  __bf16* Wkv  = (__bf16*)(ws);                // bf16; over XK (dead after GEMMs)
  __bf16* Rwkv = (__bf16*)(ws + 2 * SZ_BF);    // over XR (dead after R-GEMM)
  __bf16* Rb   = (__bf16*)d_out;               // d_out as scratch until final GEMM

  detect_small_kernel<<<dim3(1), dim3(256), 0, stream>>>(
      tdec, tfirst, lng, lnb, tmk, tmv, tmr,
      flag, tdecF, tfirstF, lngF, lnbF, tmkF, tmvF, tmrF);

  convert_w_kernel<<<dim3(512), dim3(256), 0, stream>>>(Wk, WkB, flag);
  convert_w_kernel<<<dim3(512), dim3(256), 0, stream>>>(Wv, WvB, flag);
  convert_w_kernel<<<dim3(512), dim3(256), 0, stream>>>(Wr, WrB, flag);
  convert_w_kernel<<<dim3(512), dim3(256), 0, stream>>>(Wo, WoB, flag);

  mix_kernel<<<dim3(4096), dim3(256), 0, stream>>>(x, tmkF, tmvF, tmrF, flag, XK, XV, XR);

  // 128x256 tiles: (16384/128)*(2048/256) = 128*8 = 1024 blocks, 512 thr
  dim3 g(1024), blk(512);
  gemm_bt<3><<<g, blk, 0, stream>>>(XK, WkB, (void*)Kb, flag, MM, DD, DD);
  gemm_bt<3><<<g, blk, 0, stream>>>(XV, WvB, (void*)Vb, flag, MM, DD, DD);
  gemm_bt<2><<<g, blk, 0, stream>>>(XR, WrB, (void*)Rb, flag, MM, DD, DD);

  // 4-wide wkv: B*WC*D/4 = 131072 threads -> 512 blocks; scan 16 blocks
  wkv_part_kernel<<<dim3(512), dim3(256), 0, stream>>>(Kb, Vb, pM, pA, pB);
  wkv_scan_kernel<<<dim3(16), dim3(256), 0, stream>>>(pM, pA, pB);
  wkv_out_kernel<<<dim3(512), dim3(256), 0, stream>>>(Kb, Vb, pM, pA, pB, tfirstF, Wkv);

  ln_kernel<<<dim3(MM), dim3(256), 0, stream>>>(Wkv, Rb, lngF, lnbF, Rwkv);

  gemm_bt<1><<<g, blk, 0, stream>>>(Rwkv, WoB, d_out, flag, MM, DD, DD);
}

// Round 13
// 856.887 us; speedup vs baseline: 1.0676x; 1.0024x over previous
//
#include <hip/hip_runtime.h>
#include <hip/hip_bf16.h>
#include <stdint.h>

// Problem constants
#define BB 4
#define TT 4096
#define DD 2048
#define MM (BB*TT)   // 16384 rows
#define WC 128       // wkv chunks per sequence (r13: 64->128 for 2x TLP)
#define WL 32        // wkv chunk length (WC*WL == TT)

typedef __bf16 bf16x8 __attribute__((ext_vector_type(8)));
typedef __bf16 bf16x4 __attribute__((ext_vector_type(4)));
typedef float  f32x4  __attribute__((ext_vector_type(4)));

__device__ __forceinline__ void g2l16(const void* g, void* l) {
  __builtin_amdgcn_global_load_lds(
      (const __attribute__((address_space(1))) void*)g,
      (__attribute__((address_space(3))) void*)l,
      16, 0, 0);
}

// ---------------------------------------------------------------------------
// Kernel 0: dtype detect + convert small vectors to fp32.
// ---------------------------------------------------------------------------
__global__ void detect_small_kernel(const void* __restrict__ tdec_raw,
                                    const void* __restrict__ tfirst_raw,
                                    const void* __restrict__ lng_raw,
                                    const void* __restrict__ lnb_raw,
                                    const void* __restrict__ tmk_raw,
                                    const void* __restrict__ tmv_raw,
                                    const void* __restrict__ tmr_raw,
                                    int* __restrict__ flag,
                                    float* __restrict__ tdecF,
                                    float* __restrict__ tfirstF,
                                    float* __restrict__ lngF,
                                    float* __restrict__ lnbF,
                                    float* __restrict__ tmkF,
                                    float* __restrict__ tmvF,
                                    float* __restrict__ tmrF)
{
  const uint32_t w0 = *(const uint32_t*)tdec_raw;
  const int isf32 = ((w0 & 0xFFFFu) == 0u) ? 1 : 0;
  if (threadIdx.x == 0) *flag = isf32;
  for (int d = threadIdx.x; d < DD; d += blockDim.x) {
    if (isf32) {
      tdecF[d]   = ((const float*)tdec_raw)[d];
      tfirstF[d] = ((const float*)tfirst_raw)[d];
      lngF[d]    = ((const float*)lng_raw)[d];
      lnbF[d]    = ((const float*)lnb_raw)[d];
      tmkF[d]    = ((const float*)tmk_raw)[d];
      tmvF[d]    = ((const float*)tmv_raw)[d];
      tmrF[d]    = ((const float*)tmr_raw)[d];
    } else {
      tdecF[d]   = (float)((const __bf16*)tdec_raw)[d];
      tfirstF[d] = (float)((const __bf16*)tfirst_raw)[d];
      lngF[d]    = (float)((const __bf16*)lng_raw)[d];
      lnbF[d]    = (float)((const __bf16*)lnb_raw)[d];
      tmkF[d]    = (float)((const __bf16*)tmk_raw)[d];
      tmvF[d]    = (float)((const __bf16*)tmv_raw)[d];
      tmrF[d]    = (float)((const __bf16*)tmr_raw)[d];
    }
  }
}

// ---------------------------------------------------------------------------
// Kernel 0b (r13): convert ALL FOUR DxD weight matrices in one dispatch.
// blockIdx.x >> 9 selects the matrix; low 9 bits replicate the old 512-block
// per-matrix grid (saves 3 launch gaps; identical per-element work).
// ---------------------------------------------------------------------------
__global__ void convert_w4_kernel(const void* __restrict__ s0,
                                  const void* __restrict__ s1,
                                  const void* __restrict__ s2,
                                  const void* __restrict__ s3,
                                  __bf16* __restrict__ d0,
                                  __bf16* __restrict__ d1,
                                  __bf16* __restrict__ d2,
                                  __bf16* __restrict__ d3,
                                  const int* __restrict__ flagp)
{
  const int isf32 = *flagp;
  const int w   = blockIdx.x >> 9;         // 0..3
  const int bid = blockIdx.x & 511;        // 0..511
  const void* src = (w == 0) ? s0 : (w == 1) ? s1 : (w == 2) ? s2 : s3;
  __bf16*     dst = (w == 0) ? d0 : (w == 1) ? d1 : (w == 2) ? d2 : d3;
  const int64_t NV = (int64_t)DD * DD / 8;
  for (int64_t v = bid * (int64_t)blockDim.x + threadIdx.x;
       v < NV; v += (int64_t)512 * blockDim.x) {
    const int64_t i = v * 8;
    bf16x8 o;
    if (isf32) {
      const float* sf = (const float*)src;
      f32x4 a = *(const f32x4*)(sf + i);
      f32x4 b = *(const f32x4*)(sf + i + 4);
      #pragma unroll
      for (int e = 0; e < 4; e++) { o[e] = (__bf16)a[e]; o[e+4] = (__bf16)b[e]; }
    } else {
      o = *(const bf16x8*)((const __bf16*)src + i);
    }
    *(bf16x8*)(dst + i) = o;
  }
}

// ---------------------------------------------------------------------------
// Kernel 1: token-shift mix -> xk, xv, xr (bf16)
// ---------------------------------------------------------------------------
__global__ void mix_kernel(const void* __restrict__ xraw,
                           const float* __restrict__ tmkF,
                           const float* __restrict__ tmvF,
                           const float* __restrict__ tmrF,
                           const int* __restrict__ flagp,
                           __bf16* __restrict__ xk,
                           __bf16* __restrict__ xv,
                           __bf16* __restrict__ xr)
{
  const int isf32 = *flagp;
  const int64_t NV = (int64_t)MM * DD / 8;
  for (int64_t v = blockIdx.x * (int64_t)blockDim.x + threadIdx.x;
       v < NV; v += (int64_t)gridDim.x * blockDim.x) {
    const int64_t i = v * 8;
    const int d = (int)(i & (DD - 1));
    const int64_t td = i & ((int64_t)TT * DD - 1);
    const bool has_prev = (td >= DD);
    float xc[8], xp[8];
    if (isf32) {
      const float* xf = (const float*)xraw;
      f32x4 a = *(const f32x4*)(xf + i);
      f32x4 b = *(const f32x4*)(xf + i + 4);
      #pragma unroll
      for (int e = 0; e < 4; e++) { xc[e] = a[e]; xc[e+4] = b[e]; }
      if (has_prev) {
        f32x4 c = *(const f32x4*)(xf + i - DD);
        f32x4 dd4 = *(const f32x4*)(xf + i - DD + 4);
        #pragma unroll
        for (int e = 0; e < 4; e++) { xp[e] = c[e]; xp[e+4] = dd4[e]; }
      } else {
        #pragma unroll
        for (int e = 0; e < 8; e++) xp[e] = 0.f;
      }
    } else {
      const __bf16* xb = (const __bf16*)xraw;
      bf16x8 a = *(const bf16x8*)(xb + i);
      #pragma unroll
      for (int e = 0; e < 8; e++) xc[e] = (float)a[e];
      if (has_prev) {
        bf16x8 c = *(const bf16x8*)(xb + i - DD);
        #pragma unroll
        for (int e = 0; e < 8; e++) xp[e] = (float)c[e];
      } else {
        #pragma unroll
        for (int e = 0; e < 8; e++) xp[e] = 0.f;
      }
    }
    bf16x8 ok, ov, orr;
    #pragma unroll
    for (int e = 0; e < 8; e++) {
      const float diff = xc[e] - xp[e];
      ok[e]  = (__bf16)(xp[e] + tmkF[d + e] * diff);
      ov[e]  = (__bf16)(xp[e] + tmvF[d + e] * diff);
      orr[e] = (__bf16)(xp[e] + tmrF[d + e] * diff);
    }
    *(bf16x8*)(xk + i) = ok;
    *(bf16x8*)(xv + i) = ov;
    *(bf16x8*)(xr + i) = orr;
  }
}

// ---------------------------------------------------------------------------
// Kernel 2: GEMM (r10-r12 verbatim — FROZEN at structural plateau: 163us,
// occ 40%, LDS-read-pipe bound [1528 cyc/tile measured == 1536 model:
// 128 ds_read_b128 x 12cyc per 2-block tile-instance; MFMA needs 1280].
// LDS-bytes/FLOP minimized by per-wave 64x64 (harmonic-mean optimum);
// bigger wave-tiles break the 128-reg/4-wave-SIMD budget [r3: 171us@2w,
// r7: 300us starved]. Design space closed over 12 rounds.)
// 128x256 tile, 8 waves, BK=32, dbuf 48 KiB, launch_bounds(512,4) ->
// 2 blocks/CU. r6 swizzle, r8 A-reuse XCD map, counted vmcnt, setprio.
// EPI: 0=f32, 1=final(flag?f32:bf16), 2=sigmoid->bf16, 3=bf16.
// ---------------------------------------------------------------------------
#define BARX()   __builtin_amdgcn_s_barrier()
#define SCHEDB() __builtin_amdgcn_sched_barrier(0)
#define WAITL(n) asm volatile("s_waitcnt lgkmcnt(" #n ")" ::: "memory")
#define WAITV(n) asm volatile("s_waitcnt vmcnt(" #n ")" ::: "memory")

#define STG_A(PB, kt) \
    g2l16(Asrc + (size_t)(kt)*32, smem + (PB) + tid*8)
#define STG_B(PB, kt) do { \
    g2l16(Bsrc + (size_t)(kt)*32,                 smem + (PB) + 4096 + tid*8); \
    g2l16(Bsrc + (size_t)128*Kd + (size_t)(kt)*32, smem + (PB) + 8192 + tid*8); \
  } while (0)

#define RD_A(pb) do { _Pragma("unroll") for (int i_ = 0; i_ < 4; i_++) \
    af[i_] = *(const bf16x8*)(smem + (pb) + aoff + i_*512); } while (0)
#define RD_B(pb) do { _Pragma("unroll") for (int j_ = 0; j_ < 4; j_++) \
    bfr[j_] = *(const bf16x8*)(smem + (pb) + boff + j_*512); } while (0)

#define MFMA_J(J) do { _Pragma("unroll") for (int i_ = 0; i_ < 4; i_++) \
    acc[i_][J] = __builtin_amdgcn_mfma_f32_16x16x32_bf16(af[i_], bfr[J], acc[i_][J], 0, 0, 0); } while (0)

#define TILE32(CB, OB, tA, tB) do { \
    RD_A(CB); RD_B(CB); \
    STG_A(OB, tA); \
    __builtin_amdgcn_s_setprio(1); \
    MFMA_J(0); MFMA_J(1); \
    __builtin_amdgcn_s_setprio(0); \
    WAITL(0); \
    BARX(); \
    SCHEDB(); \
    STG_B(CB, tB); \
    __builtin_amdgcn_s_setprio(1); \
    MFMA_J(2); MFMA_J(3); \
    __builtin_amdgcn_s_setprio(0); \
    WAITV(2); \
    BARX(); \
    SCHEDB(); \
  } while (0)

template <int EPI>
__global__ void __launch_bounds__(512, 4)
gemm_bt(const __bf16* __restrict__ A,
        const __bf16* __restrict__ Bm,
        void* __restrict__ Cout,
        const int* __restrict__ flagp,
        int Md, int Nd, int Kd)
{
  __shared__ __bf16 smem[24576];   // 48 KiB -> 2 blocks/CU
  const int isf32 = (EPI == 1) ? *flagp : 0;
  const int tid  = threadIdx.x;    // 0..511
  const int lane = tid & 63;
  const int wv   = tid >> 6;       // 0..7
  const int wm   = wv >> 2;        // wave row 0..1 (64 rows each)
  const int wn   = wv & 3;         // wave col 0..3 (64 cols each)
  const int l16  = lane & 15;
  const int qd   = lane >> 4;

  // A-reuse XCD map (r8): the 8 colblk-sharers of one A panel are stride-8
  // in bid -> same XCD.
  const int bid    = blockIdx.x;          // 0..1023
  const int xcd    = bid & 7;
  const int colblk = (bid >> 3) & 7;
  const int rowsub = bid >> 6;            // 0..15
  const int row0   = (xcd * 16 + rowsub) * 128;
  const int col0   = colblk * 256;

  // staging: thread -> row tid>>2 (0..127), phys chunk tid&3; global chunk
  // inverse-swizzled with row bits [2:1] (r6 pattern, 0 conflicts measured).
  const int srow   = tid >> 2;
  const int schunk = (tid & 3) ^ ((srow >> 1) & 3);
  const __bf16* Asrc = A  + (size_t)(row0 + srow) * Kd + schunk * 8;
  const __bf16* Bsrc = Bm + (size_t)(col0 + srow) * Kd + schunk * 8;

  // ds_read: fragment row = w*64 + f*16 + l16 -> (row>>1)&3 == (l16>>1)&3
  const int c0   = (qd ^ ((l16 >> 1) & 3)) * 8;
  const int aoff = (wm * 64 + l16) * 32 + c0;
  const int boff = 4096 + (wn * 64 + l16) * 32 + c0;

  f32x4 acc[4][4];
  #pragma unroll
  for (int i = 0; i < 4; i++)
    #pragma unroll
    for (int j = 0; j < 4; j++)
      acc[i][j] = (f32x4){0.f, 0.f, 0.f, 0.f};

  bf16x8 af[4], bfr[4];

  // Prologue: tile0 A+B -> buf0, tile1 B -> buf1. WAITV(2) drains A0,B0
  // (FIFO), leaves tile1.B (2) = steady-state invariant.
  STG_A(0, 0);
  STG_B(0, 0);
  STG_B(12288, 1);
  WAITV(2);
  BARX();
  SCHEDB();

  // 64 K-tiles. Main loop t=0..61 (stages A(1..62), B(2..63)); tail 62,63.
  #pragma unroll 1
  for (int it = 0; it < 31; ++it) {
    const int t = it << 1;
    TILE32(0,     12288, t + 1, t + 2);
    TILE32(12288, 0,     t + 2, t + 3);
  }

  // tile 62 (buf0): stage only A(63)->buf1 (B(63) staged at t=61); drain.
  {
    RD_A(0); RD_B(0);
    STG_A(12288, 63);
    __builtin_amdgcn_s_setprio(1);
    MFMA_J(0); MFMA_J(1); MFMA_J(2); MFMA_J(3);
    __builtin_amdgcn_s_setprio(0);
    WAITV(0);
    BARX();
    SCHEDB();
  }
  // tile 63 (buf1): no staging, no barriers.
  {
    RD_A(12288); RD_B(12288);
    __builtin_amdgcn_s_setprio(1);
    MFMA_J(0); MFMA_J(1); MFMA_J(2); MFMA_J(3);
    __builtin_amdgcn_s_setprio(0);
  }

  // epilogue: C/D layout col=lane&15, row=quad*4+reg (verified m89/m91)
  #pragma unroll
  for (int i = 0; i < 4; i++) {
    const int rb = row0 + wm * 64 + i * 16 + qd * 4;
    #pragma unroll
    for (int j = 0; j < 4; j++) {
      const int c = col0 + wn * 64 + j * 16 + l16;
      #pragma unroll
      for (int reg = 0; reg < 4; reg++) {
        const size_t idx = (size_t)(rb + reg) * Nd + c;
        float v = acc[i][j][reg];
        if (EPI == 0) {
          ((float*)Cout)[idx] = v;
        } else if (EPI == 1) {
          if (isf32) ((float*)Cout)[idx] = v;
          else       ((__bf16*)Cout)[idx] = (__bf16)v;
        } else if (EPI == 3) {
          ((__bf16*)Cout)[idx] = (__bf16)v;
        } else {
          float s = 1.f / (1.f + __expf(-v));
          ((__bf16*)Cout)[idx] = (__bf16)s;
        }
      }
    }
  }
}

// ---------------------------------------------------------------------------
// WKV parallel log-sum-exp prefix sum. r13: WC=128/WL=32 -> part/out run
// 1024 blocks (16 waves/CU vs 8) with half the per-thread serial depth —
// attacks latency exposure on the 8KB-stride walk. bf16 K/V, 4-wide.
// ---------------------------------------------------------------------------
__global__ void wkv_part_kernel(const __bf16* __restrict__ Kb,
                                const __bf16* __restrict__ Vb,
                                float* __restrict__ pM,
                                float* __restrict__ pA,
                                float* __restrict__ pB)
{
  const int gid = blockIdx.x * blockDim.x + threadIdx.x;  // 0..B*WC*D/4-1
  const int d = (gid & (DD / 4 - 1)) * 4;
  const int rest = gid >> 9;               // DD/4 = 512 = 2^9
  const int c = rest & (WC - 1);
  const int b = rest >> 7;                 // log2(WC) = 7
  const __bf16* kp = Kb + ((size_t)b * TT + (size_t)c * WL) * DD + d;
  const __bf16* vp = Vb + ((size_t)b * TT + (size_t)c * WL) * DD + d;
  float M0 = -1e38f, A0 = 0.f, B0 = 0.f;
  float M1 = -1e38f, A1 = 0.f, B1 = 0.f;
  float M2 = -1e38f, A2 = 0.f, B2 = 0.f;
  float M3 = -1e38f, A3 = 0.f, B3 = 0.f;
  #define PSTEP(Mv, Av, Bv2, kf, vf) do { \
      const float q = fmaxf(Mv, kf); \
      const float s = __expf(Mv - q); \
      const float e = __expf((kf) - q); \
      Av = Av * s + e * (vf); \
      Bv2 = Bv2 * s + e; \
      Mv = q; \
    } while (0)
  for (int t = 0; t < WL; t++) {
    const bf16x4 k4 = *(const bf16x4*)(kp + (size_t)t * DD);
    const bf16x4 v4 = *(const bf16x4*)(vp + (size_t)t * DD);
    PSTEP(M0, A0, B0, (float)k4[0], (float)v4[0]);
    PSTEP(M1, A1, B1, (float)k4[1], (float)v4[1]);
    PSTEP(M2, A2, B2, (float)k4[2], (float)v4[2]);
    PSTEP(M3, A3, B3, (float)k4[3], (float)v4[3]);
  }
  const size_t pi = ((size_t)b * WC + c) * DD + d;
  *(f32x4*)(pM + pi) = (f32x4){M0, M1, M2, M3};
  *(f32x4*)(pA + pi) = (f32x4){A0, A1, A2, A3};
  *(f32x4*)(pB + pi) = (f32x4){B0, B1, B2, B3};
}

__global__ void wkv_scan_kernel(float* __restrict__ pM,
                                float* __restrict__ pA,
                                float* __restrict__ pB)
{
  const int gid = blockIdx.x * blockDim.x + threadIdx.x;  // 0..B*D/2-1
  const int d = (gid & (DD / 2 - 1)) * 2;
  const int b = gid >> 10;
  float M0 = -1e38f, A0 = 0.f, B0 = 0.f;
  float M1 = -1e38f, A1 = 0.f, B1 = 0.f;
  for (int c = 0; c < WC; c++) {
    const size_t pi = ((size_t)b * WC + c) * DD + d;
    const float2 m2 = *(const float2*)(pM + pi);
    const float2 a2 = *(const float2*)(pA + pi);
    const float2 b2 = *(const float2*)(pB + pi);
    *(float2*)(pM + pi) = make_float2(M0, M1);
    *(float2*)(pA + pi) = make_float2(A0, A1);
    *(float2*)(pB + pi) = make_float2(B0, B1);
    {
      const float q = fmaxf(M0, m2.x);
      const float s0 = __expf(M0 - q);
      const float s1 = __expf(m2.x - q);
      A0 = A0 * s0 + a2.x * s1;
      B0 = B0 * s0 + b2.x * s1;
      M0 = q;
    }
    {
      const float q = fmaxf(M1, m2.y);
      const float s0 = __expf(M1 - q);
      const float s1 = __expf(m2.y - q);
      A1 = A1 * s0 + a2.y * s1;
      B1 = B1 * s0 + b2.y * s1;
      M1 = q;
    }
  }
}

__global__ void wkv_out_kernel(const __bf16* __restrict__ Kb,
                               const __bf16* __restrict__ Vb,
                               const float* __restrict__ pM,
                               const float* __restrict__ pA,
                               const float* __restrict__ pB,
                               const float* __restrict__ tfirstF,
                               __bf16* __restrict__ out)
{
  const int gid = blockIdx.x * blockDim.x + threadIdx.x;  // 0..B*WC*D/4-1
  const int d = (gid & (DD / 4 - 1)) * 4;
  const int rest = gid >> 9;
  const int c = rest & (WC - 1);
  const int b = rest >> 7;
  const size_t pi = ((size_t)b * WC + c) * DD + d;
  f32x4 M4 = *(const f32x4*)(pM + pi);
  f32x4 A4 = *(const f32x4*)(pA + pi);
  f32x4 B4 = *(const f32x4*)(pB + pi);
  float M0 = M4[0], A0 = A4[0], B0 = B4[0];
  float M1 = M4[1], A1 = A4[1], B1 = B4[1];
  float M2 = M4[2], A2 = A4[2], B2 = B4[2];
  float M3 = M4[3], A3 = A4[3], B3 = B4[3];
  const f32x4 u4 = *(const f32x4*)(tfirstF + d);
  const size_t base = ((size_t)b * TT + (size_t)c * WL) * DD + d;
  const __bf16* kp = Kb + base;
  const __bf16* vp = Vb + base;
  __bf16*       op = out + base;
  #define OSTEP(Mv, Av, Bv2, kf, vf, uf, oref) do { \
      const float ku = (kf) + (uf); \
      const float qo = fmaxf(Mv, ku); \
      const float so = __expf(Mv - qo); \
      const float eo = __expf(ku - qo); \
      oref = (__bf16)__fdividef(Av * so + (vf) * eo, Bv2 * so + eo); \
      const float q = fmaxf(Mv, kf); \
      const float s = __expf(Mv - q); \
      const float e = __expf((kf) - q); \
      Av = Av * s + e * (vf); \
      Bv2 = Bv2 * s + e; \
      Mv = q; \
    } while (0)
  for (int t = 0; t < WL; t++) {
    const bf16x4 k4 = *(const bf16x4*)(kp + (size_t)t * DD);
    const bf16x4 v4 = *(const bf16x4*)(vp + (size_t)t * DD);
    bf16x4 o4;
    OSTEP(M0, A0, B0, (float)k4[0], (float)v4[0], u4[0], o4[0]);
    OSTEP(M1, A1, B1, (float)k4[1], (float)v4[1], u4[1], o4[1]);
    OSTEP(M2, A2, B2, (float)k4[2], (float)v4[2], u4[2], o4[2]);
    OSTEP(M3, A3, B3, (float)k4[3], (float)v4[3], u4[3], o4[3]);
    *(bf16x4*)(op + (size_t)t * DD) = o4;
  }
}

// ---------------------------------------------------------------------------
// Kernel 4: LayerNorm over D + multiply by r -> rwkv (bf16). bf16 wkv input,
// 8-consecutive-element vectorized loads/stores (16 B/lane).
// ---------------------------------------------------------------------------
__global__ void ln_kernel(const __bf16* __restrict__ wkv,
                          const __bf16* __restrict__ rbuf,
                          const float* __restrict__ g,
                          const float* __restrict__ beta,
                          __bf16* __restrict__ out)
{
  const int row = blockIdx.x;
  const int tid = threadIdx.x;
  const size_t base = (size_t)row * DD + (size_t)tid * 8;

  bf16x8 w8 = *(const bf16x8*)(wkv + base);
  float vals[8];
  float s = 0.f, sq = 0.f;
  #pragma unroll
  for (int e = 0; e < 8; e++) {
    const float v = (float)w8[e];
    vals[e] = v;
    s += v;
    sq += v * v;
  }
  #pragma unroll
  for (int off = 1; off < 64; off <<= 1) {
    s  += __shfl_xor(s, off);
    sq += __shfl_xor(sq, off);
  }
  __shared__ float ls[4], lsq[4];
  const int wave = tid >> 6;
  if ((tid & 63) == 0) { ls[wave] = s; lsq[wave] = sq; }
  __syncthreads();
  s  = ls[0] + ls[1] + ls[2] + ls[3];
  sq = lsq[0] + lsq[1] + lsq[2] + lsq[3];

  const float mu = s * (1.f / DD);
  const float var = sq * (1.f / DD) - mu * mu;
  const float rs = rsqrtf(var + 1e-5f);

  bf16x8 r8 = *(const bf16x8*)(rbuf + base);
  f32x4 g0 = *(const f32x4*)(g + tid * 8);
  f32x4 g1 = *(const f32x4*)(g + tid * 8 + 4);
  f32x4 be0 = *(const f32x4*)(beta + tid * 8);
  f32x4 be1 = *(const f32x4*)(beta + tid * 8 + 4);

  bf16x8 o8;
  #pragma unroll
  for (int e = 0; e < 4; e++) {
    const float v0 = (vals[e] - mu) * rs * g0[e] + be0[e];
    const float v1 = (vals[e + 4] - mu) * rs * g1[e] + be1[e];
    o8[e]     = (__bf16)((float)r8[e]     * v0);
    o8[e + 4] = (__bf16)((float)r8[e + 4] * v1);
  }
  *(bf16x8*)(out + base) = o8;
}

// ---------------------------------------------------------------------------
extern "C" void kernel_launch(void* const* d_in, const int* in_sizes, int n_in,
                              void* d_out, int out_size, void* d_ws, size_t ws_size,
                              hipStream_t stream) {
  const void* x      = d_in[0];
  const void* Wk     = d_in[1];
  const void* Wv     = d_in[2];
  const void* Wr     = d_in[3];
  const void* Wo     = d_in[4];
  const void* tmk    = d_in[5];
  const void* tmv    = d_in[6];
  const void* tmr    = d_in[7];
  const void* tdec   = d_in[8];
  const void* tfirst = d_in[9];
  const void* lng    = d_in[10];
  const void* lnb    = d_in[11];

  char* ws = (char*)d_ws;
  const size_t SZ_BF = (size_t)MM * DD * 2;   // 64 MiB
  const size_t SZ_F  = (size_t)MM * DD * 4;   // 128 MiB
  const size_t SZ_W  = (size_t)DD * DD * 2;   // 8 MiB
  __bf16* XK   = (__bf16*)(ws);
  __bf16* XV   = (__bf16*)(ws + SZ_BF);
  __bf16* XR   = (__bf16*)(ws + 2 * SZ_BF);
  __bf16* Kb   = (__bf16*)(ws + 3 * SZ_BF);          // bf16 (slot is 128MB)
  char*   VbSlot = ws + 3 * SZ_BF + SZ_F;            // 128 MiB slot
  __bf16* Vb   = (__bf16*)VbSlot;                    // bf16: first 64 MiB
  // prefix arrays in the free upper half of the Vb slot (12 MiB total at
  // WC=128; no aliasing with Wkv / Rwkv regions).
  float* pM = (float*)(VbSlot + SZ_BF);
  float* pA = pM + (size_t)BB * WC * DD;
  float* pB = pA + (size_t)BB * WC * DD;
  __bf16* WkB  = (__bf16*)(ws + 3 * SZ_BF + 2 * SZ_F);
  __bf16* WvB  = (__bf16*)(ws + 3 * SZ_BF + 2 * SZ_F + SZ_W);
  __bf16* WrB  = (__bf16*)(ws + 3 * SZ_BF + 2 * SZ_F + 2 * SZ_W);
  __bf16* WoB  = (__bf16*)(ws + 3 * SZ_BF + 2 * SZ_F + 3 * SZ_W);
  char*   smal = ws + 3 * SZ_BF + 2 * SZ_F + 4 * SZ_W;
  int*    flag    = (int*)smal;
  float*  tdecF   = (float*)(smal + 64);
  float*  tfirstF = tdecF + DD;
  float*  lngF    = tdecF + 2 * DD;
  float*  lnbF    = tdecF + 3 * DD;
  float*  tmkF    = tdecF + 4 * DD;
  float*  tmvF    = tdecF + 5 * DD;
  float*  tmrF    = tdecF + 6 * DD;
  __bf16* Wkv  = (__bf16*)(ws);                // bf16; over XK (dead after GEMMs)
  __bf16* Rwkv = (__bf16*)(ws + 2 * SZ_BF);    // over XR (dead after R-GEMM)
  __bf16* Rb   = (__bf16*)d_out;               // d_out as scratch until final GEMM

  detect_small_kernel<<<dim3(1), dim3(256), 0, stream>>>(
      tdec, tfirst, lng, lnb, tmk, tmv, tmr,
      flag, tdecF, tfirstF, lngF, lnbF, tmkF, tmvF, tmrF);

  // r13: all four weight conversions in one dispatch (2048 blocks)
  convert_w4_kernel<<<dim3(2048), dim3(256), 0, stream>>>(
      Wk, Wv, Wr, Wo, WkB, WvB, WrB, WoB, flag);

  mix_kernel<<<dim3(4096), dim3(256), 0, stream>>>(x, tmkF, tmvF, tmrF, flag, XK, XV, XR);

  // 128x256 tiles: (16384/128)*(2048/256) = 128*8 = 1024 blocks, 512 thr
  dim3 g(1024), blk(512);
  gemm_bt<3><<<g, blk, 0, stream>>>(XK, WkB, (void*)Kb, flag, MM, DD, DD);
  gemm_bt<3><<<g, blk, 0, stream>>>(XV, WvB, (void*)Vb, flag, MM, DD, DD);
  gemm_bt<2><<<g, blk, 0, stream>>>(XR, WrB, (void*)Rb, flag, MM, DD, DD);

  // 4-wide wkv at WC=128: B*WC*D/4 = 262144 threads -> 1024 blocks
  wkv_part_kernel<<<dim3(1024), dim3(256), 0, stream>>>(Kb, Vb, pM, pA, pB);
  wkv_scan_kernel<<<dim3(16), dim3(256), 0, stream>>>(pM, pA, pB);
  wkv_out_kernel<<<dim3(1024), dim3(256), 0, stream>>>(Kb, Vb, pM, pA, pB, tfirstF, Wkv);

  ln_kernel<<<dim3(MM), dim3(256), 0, stream>>>(Wkv, Rb, lngF, lnbF, Rwkv);

  gemm_bt<1><<<g, blk, 0, stream>>>(Rwkv, WoB, d_out, flag, MM, DD, DD);
}